// Round 5
// baseline (433.526 us; speedup 1.0000x reference)
//
#include <hip/hip_runtime.h>

#define NTOK 2304   // 48*48 tokens
#define NH 12
#define HD 64

typedef __attribute__((ext_vector_type(8))) short bf16x8;
typedef __attribute__((ext_vector_type(4))) float f32x4;

__device__ __forceinline__ unsigned short f2bf(float f){
  union { float f; unsigned u; } v; v.f = f;
  unsigned r = v.u + 0x7fffu + ((v.u >> 16) & 1u);
  return (unsigned short)(r >> 16);
}
__device__ __forceinline__ float bf2f(unsigned short h){
  union { unsigned u; float f; } v; v.u = ((unsigned)h) << 16;
  return v.f;
}
__device__ __forceinline__ void gload_lds16(const void* g, void* lds){
  __builtin_amdgcn_global_load_lds(
    (const __attribute__((address_space(1))) unsigned int*)g,
    (__attribute__((address_space(3))) unsigned int*)lds, 16, 0, 0);
}

// ---------------- fp32 -> bf16 convert ----------------
__global__ __launch_bounds__(256) void cvt_f32_bf16(const float* __restrict__ src,
                                                    unsigned short* __restrict__ dst, int n4){
  int i = blockIdx.x * 256 + threadIdx.x;
  if (i >= n4) return;
  float4 v = ((const float4*)src)[i];
  union { unsigned short u[4]; unsigned long long ll; } o;
  o.u[0] = f2bf(v.x); o.u[1] = f2bf(v.y); o.u[2] = f2bf(v.z); o.u[3] = f2bf(v.w);
  ((unsigned long long*)dst)[i] = o.ll;
}

// ---------------- LoRA t = x @ A^T  (t[3][2304][4]) ----------------
__global__ __launch_bounds__(256) void lora_t_kernel(const float* __restrict__ x,
    const float* __restrict__ Aq, const float* __restrict__ Ak, const float* __restrict__ Av,
    float* __restrict__ t){
  int wave = (blockIdx.x * 256 + threadIdx.x) >> 6;   // token
  int lane = threadIdx.x & 63;
  if (wave >= NTOK) return;
  const float* xr = x + (size_t)wave * 768;
  float part[12];
  #pragma unroll
  for (int j = 0; j < 12; j++) part[j] = 0.f;
  for (int k = lane; k < 768; k += 64){
    float xv = xr[k];
    #pragma unroll
    for (int r = 0; r < 4; r++){
      part[r]     += xv * Aq[r*768 + k];
      part[4 + r] += xv * Ak[r*768 + k];
      part[8 + r] += xv * Av[r*768 + k];
    }
  }
  #pragma unroll
  for (int j = 0; j < 12; j++){
    float v = part[j];
    #pragma unroll
    for (int off = 32; off; off >>= 1) v += __shfl_xor(v, off);
    if (lane == 0){
      int mat = j >> 2, r = j & 3;
      t[((size_t)mat * NTOK + wave) * 4 + r] = v;
    }
  }
}

// ---------------- fused qkv GEMM (+bias +LoRA, writes q(scaled),k,vT) ----------------
__global__ __launch_bounds__(256) void qkv_gemm(
    const unsigned short* __restrict__ xg,   // [2304][768] bf16
    const unsigned short* __restrict__ wg,   // [2304][768] bf16
    const float* __restrict__ bias,          // [2304]
    const float* __restrict__ t,             // [3][2304][4]
    const float* __restrict__ Bq, const float* __restrict__ Bk, const float* __restrict__ Bv, // [768][4]
    unsigned short* __restrict__ qo,         // [12][2304][64]  (pre-scaled by 0.125)
    unsigned short* __restrict__ ko,         // [12][2304][64]
    unsigned short* __restrict__ vT)         // [12][64][2304]
{
  __shared__ short As[128*64];
  __shared__ short Bs[128*64];
  const int tid = threadIdx.x;
  const int lane = tid & 63;
  const int wv = tid >> 6;
  const int r = lane & 15, g = lane >> 4;
  const int wm = (wv >> 1) * 64, wn = (wv & 1) * 64;
  const int m0 = blockIdx.y * 128, n0 = blockIdx.x * 128;

  f32x4 acc[4][4];
  #pragma unroll
  for (int i = 0; i < 4; i++)
    #pragma unroll
    for (int j = 0; j < 4; j++) acc[i][j] = (f32x4){0.f, 0.f, 0.f, 0.f};

  for (int k0 = 0; k0 < 768; k0 += 64){
    __syncthreads();
    #pragma unroll
    for (int it = 0; it < 4; it++){
      int f = it * 256 + tid;
      int row = f >> 3, u = f & 7;
      int us = ((u ^ (row & 7)) << 3);
      gload_lds16(xg + (size_t)(m0 + row) * 768 + k0 + us, &As[f * 8]);
      gload_lds16(wg + (size_t)(n0 + row) * 768 + k0 + us, &Bs[f * 8]);
    }
    __syncthreads();
    #pragma unroll
    for (int ks = 0; ks < 2; ks++){
      bf16x8 af[4], bfr[4];
      #pragma unroll
      for (int mt = 0; mt < 4; mt++){
        int row = wm + mt * 16 + r;
        af[mt] = *(const bf16x8*)&As[row * 64 + ((((ks << 2) | g) ^ (r & 7)) << 3)];
      }
      #pragma unroll
      for (int nt = 0; nt < 4; nt++){
        int row = wn + nt * 16 + r;
        bfr[nt] = *(const bf16x8*)&Bs[row * 64 + ((((ks << 2) | g) ^ (r & 7)) << 3)];
      }
      #pragma unroll
      for (int mt = 0; mt < 4; mt++)
        #pragma unroll
        for (int nt = 0; nt < 4; nt++)
          acc[mt][nt] = __builtin_amdgcn_mfma_f32_16x16x32_bf16(af[mt], bfr[nt], acc[mt][nt], 0, 0, 0);
    }
  }

  const int part = n0 / 768;
  const float* Bl = (part == 0) ? Bq : ((part == 1) ? Bk : Bv);
  const float* tp = t + (size_t)part * NTOK * 4;
  #pragma unroll
  for (int mt = 0; mt < 4; mt++){
    #pragma unroll
    for (int reg = 0; reg < 4; reg++){
      int row_m = m0 + wm + mt * 16 + g * 4 + reg;
      float4 tv = *(const float4*)&tp[row_m * 4];
      #pragma unroll
      for (int nt = 0; nt < 4; nt++){
        int col = n0 + wn + nt * 16 + r;
        int cc = col - part * 768;
        float4 bw = *(const float4*)&Bl[cc * 4];
        float val = acc[mt][nt][reg] + bias[col]
                  + 0.25f * (tv.x * bw.x + tv.y * bw.y + tv.z * bw.z + tv.w * bw.w);
        int head = cc >> 6, d = cc & 63;
        if (part == 0)      qo[((size_t)head * NTOK + row_m) * 64 + d] = f2bf(val * 0.125f);
        else if (part == 1) ko[((size_t)head * NTOK + row_m) * 64 + d] = f2bf(val);
        else                vT[((size_t)head * 64 + d) * NTOK + row_m] = f2bf(val);
      }
    }
  }
}

// ---------------- rel_h / rel_w via MFMA ----------------
__global__ __launch_bounds__(256, 2) void rel_gemm(
    const unsigned short* __restrict__ qg,    // [12][2304][64] bf16 (scaled by 0.125)
    const unsigned short* __restrict__ rphb,  // [95][64] bf16
    const unsigned short* __restrict__ rpwb,  // [95][64] bf16
    float* __restrict__ rel_h,                // [12][2304][48]
    float* __restrict__ rel_w)                // [12][2304][48]
{
  __shared__ float G[48 * 196];
  const int ih = blockIdx.x, head = blockIdx.y;
  const int tid = threadIdx.x, lane = tid & 63, wv = tid >> 6;
  const int r = lane & 15, g = lane >> 4;
  const int q0 = ih * 48;

  bf16x8 af[3][2];
  #pragma unroll
  for (int mt = 0; mt < 3; mt++)
    #pragma unroll
    for (int ks = 0; ks < 2; ks++)
      af[mt][ks] = *(const bf16x8*)&qg[((size_t)head * NTOK + q0 + mt * 16 + r) * 64 + ks * 32 + g * 8];

  bf16x8 bf[3][2];
  #pragma unroll
  for (int nt = 0; nt < 3; nt++){
    int col = wv * 48 + nt * 16 + r;
    const unsigned short* src = (col < 95) ? &rphb[(size_t)col * 64]
                              : (col < 190) ? &rpwb[(size_t)(col - 95) * 64]
                              : &rpwb[0];
    #pragma unroll
    for (int ks = 0; ks < 2; ks++)
      bf[nt][ks] = *(const bf16x8*)&src[ks * 32 + g * 8];
  }

  f32x4 acc[3][3];
  #pragma unroll
  for (int mt = 0; mt < 3; mt++)
    #pragma unroll
    for (int nt = 0; nt < 3; nt++) acc[mt][nt] = (f32x4){0.f, 0.f, 0.f, 0.f};
  #pragma unroll
  for (int ks = 0; ks < 2; ks++)
    #pragma unroll
    for (int mt = 0; mt < 3; mt++)
      #pragma unroll
      for (int nt = 0; nt < 3; nt++)
        acc[mt][nt] = __builtin_amdgcn_mfma_f32_16x16x32_bf16(af[mt][ks], bf[nt][ks], acc[mt][nt], 0, 0, 0);

  #pragma unroll
  for (int mt = 0; mt < 3; mt++)
    #pragma unroll
    for (int reg = 0; reg < 4; reg++){
      int row = mt * 16 + g * 4 + reg;
      #pragma unroll
      for (int nt = 0; nt < 3; nt++)
        G[row * 196 + wv * 48 + nt * 16 + r] = acc[mt][nt][reg];
    }
  __syncthreads();

  for (int idx = tid; idx < 48 * 96; idx += 256){
    int i = idx / 96, c = idx % 96;
    size_t gi = (size_t)head * NTOK + q0 + i;
    if (c < 48) rel_h[gi * 48 + c]        = G[i * 196 + (ih + 47 - c)] * 8.f;
    else        rel_w[gi * 48 + (c - 48)] = G[i * 196 + 95 + (i + 47 - (c - 48))] * 8.f;
  }
}

// ---------------- flash attention: 32 q-rows/block, 4 waves split KV ----------------
// v4: 4 blocks/CU (VGPR fits 128, LDS 34.3KB*4 < 160KB) -> whole grid co-resident
__global__ __launch_bounds__(256, 4) void attn_kernel(
    const unsigned short* __restrict__ qg,   // [12][2304][64] scaled
    const unsigned short* __restrict__ kg,   // [12][2304][64]
    const unsigned short* __restrict__ vT,   // [12][64][2304]
    const float* __restrict__ rel_h,         // [12][2304][48]
    const float* __restrict__ rel_w,         // [12][2304][48]
    unsigned short* __restrict__ ao)         // [2304][768]
{
  __shared__ __align__(16) char smem[32768 + 1152];
  float* rel_s = (float*)smem;
  unsigned short* P_lds = (unsigned short*)(smem + 12800);
  float* Obuf = (float*)smem;
  float* msh = (float*)(smem + 32768);
  float* lsh = (float*)(smem + 32768 + 512);
  float* Lsh = (float*)(smem + 32768 + 1024);

  const int head = blockIdx.y;
  const int q0 = blockIdx.x * 32;
  const int tid = threadIdx.x, lane = tid & 63, wv = tid >> 6;
  const int r = lane & 15, g = lane >> 4;

  for (int idx = tid; idx < 32 * 96; idx += 256){
    int i = idx / 96, c = idx % 96;
    int token = head * NTOK + q0 + i;
    rel_s[i * 100 + c] = (c < 48) ? rel_h[(size_t)token * 48 + c]
                                  : rel_w[(size_t)token * 48 + (c - 48)];
  }
  __syncthreads();

  bf16x8 qf[2][2];
  #pragma unroll
  for (int mt = 0; mt < 2; mt++)
    #pragma unroll
    for (int ks = 0; ks < 2; ks++)
      qf[mt][ks] = *(const bf16x8*)&qg[((size_t)head * NTOK + q0 + mt * 16 + r) * 64 + ks * 32 + g * 8];

  f32x4 Oa[2][4];
  float mrun[2][4], lrun[2][4];
  #pragma unroll
  for (int mt = 0; mt < 2; mt++){
    #pragma unroll
    for (int dt = 0; dt < 4; dt++) Oa[mt][dt] = (f32x4){0.f, 0.f, 0.f, 0.f};
    #pragma unroll
    for (int reg = 0; reg < 4; reg++){ mrun[mt][reg] = -1e30f; lrun[mt][reg] = 0.f; }
  }

  unsigned short* pbase = &P_lds[wv * 32 * 72];
  const unsigned short* kbase = kg + (size_t)head * NTOK * 64;
  const unsigned short* vbase = vT + (size_t)head * 64 * NTOK;
  const int key_base = wv * 9 * 64;

  bf16x8 kc[4][2], kn[4][2];
  #pragma unroll
  for (int nt = 0; nt < 4; nt++)
    #pragma unroll
    for (int ks = 0; ks < 2; ks++)
      kc[nt][ks] = *(const bf16x8*)&kbase[(size_t)(key_base + nt * 16 + r) * 64 + ks * 32 + g * 8];

  for (int it = 0; it < 9; it++){
    int key0 = key_base + it * 64;

    bf16x8 vf[4][2];
    #pragma unroll
    for (int dt = 0; dt < 4; dt++)
      #pragma unroll
      for (int ks = 0; ks < 2; ks++)
        vf[dt][ks] = *(const bf16x8*)&vbase[(size_t)(dt * 16 + r) * NTOK + key0 + ks * 32 + g * 8];

    if (it < 8){
      #pragma unroll
      for (int nt = 0; nt < 4; nt++)
        #pragma unroll
        for (int ks = 0; ks < 2; ks++)
          kn[nt][ks] = *(const bf16x8*)&kbase[(size_t)(key0 + 64 + nt * 16 + r) * 64 + ks * 32 + g * 8];
    }

    f32x4 s[2][4];
    #pragma unroll
    for (int mt = 0; mt < 2; mt++)
      #pragma unroll
      for (int nt = 0; nt < 4; nt++) s[mt][nt] = (f32x4){0.f, 0.f, 0.f, 0.f};
    #pragma unroll
    for (int mt = 0; mt < 2; mt++)
      #pragma unroll
      for (int nt = 0; nt < 4; nt++){
        s[mt][nt] = __builtin_amdgcn_mfma_f32_16x16x32_bf16(qf[mt][0], kc[nt][0], s[mt][nt], 0, 0, 0);
        s[mt][nt] = __builtin_amdgcn_mfma_f32_16x16x32_bf16(qf[mt][1], kc[nt][1], s[mt][nt], 0, 0, 0);
      }

    int kh[4], kw[4];
    #pragma unroll
    for (int nt = 0; nt < 4; nt++){
      int key = key0 + nt * 16 + r;
      kh[nt] = key / 48; kw[nt] = key % 48;
    }
    #pragma unroll
    for (int mt = 0; mt < 2; mt++)
      #pragma unroll
      for (int reg = 0; reg < 4; reg++){
        const float* rs = &rel_s[(mt * 16 + g * 4 + reg) * 100];
        #pragma unroll
        for (int nt = 0; nt < 4; nt++)
          s[mt][nt][reg] += rs[kh[nt]] + rs[48 + kw[nt]];
      }

    #pragma unroll
    for (int mt = 0; mt < 2; mt++)
      #pragma unroll
      for (int reg = 0; reg < 4; reg++){
        float tm = fmaxf(fmaxf(s[mt][0][reg], s[mt][1][reg]), fmaxf(s[mt][2][reg], s[mt][3][reg]));
        tm = fmaxf(tm, __shfl_xor(tm, 1));
        tm = fmaxf(tm, __shfl_xor(tm, 2));
        tm = fmaxf(tm, __shfl_xor(tm, 4));
        tm = fmaxf(tm, __shfl_xor(tm, 8));
        float mold = mrun[mt][reg];
        float mnew = fmaxf(mold, tm);
        float alpha = __expf(mold - mnew);
        mrun[mt][reg] = mnew;
        float ps = 0.f;
        #pragma unroll
        for (int nt = 0; nt < 4; nt++){
          float p = __expf(s[mt][nt][reg] - mnew);
          s[mt][nt][reg] = p;
          ps += p;
        }
        ps += __shfl_xor(ps, 1);
        ps += __shfl_xor(ps, 2);
        ps += __shfl_xor(ps, 4);
        ps += __shfl_xor(ps, 8);
        lrun[mt][reg] = lrun[mt][reg] * alpha + ps;
        #pragma unroll
        for (int dt = 0; dt < 4; dt++) Oa[mt][dt][reg] *= alpha;
      }

    #pragma unroll
    for (int mt = 0; mt < 2; mt++)
      #pragma unroll
      for (int reg = 0; reg < 4; reg++){
        int prow = mt * 16 + g * 4 + reg;
        #pragma unroll
        for (int nt = 0; nt < 4; nt++)
          pbase[prow * 72 + nt * 16 + r] = f2bf(s[mt][nt][reg]);
      }

    bf16x8 pf[2][2];
    #pragma unroll
    for (int mt = 0; mt < 2; mt++)
      #pragma unroll
      for (int ks = 0; ks < 2; ks++)
        pf[mt][ks] = *(const bf16x8*)&pbase[(mt * 16 + r) * 72 + ks * 32 + g * 8];
    #pragma unroll
    for (int dt = 0; dt < 4; dt++)
      #pragma unroll
      for (int ks = 0; ks < 2; ks++)
        #pragma unroll
        for (int mt = 0; mt < 2; mt++)
          Oa[mt][dt] = __builtin_amdgcn_mfma_f32_16x16x32_bf16(pf[mt][ks], vf[dt][ks], Oa[mt][dt], 0, 0, 0);

    if (it < 8){
      #pragma unroll
      for (int nt = 0; nt < 4; nt++)
        #pragma unroll
        for (int ks = 0; ks < 2; ks++)
          kc[nt][ks] = kn[nt][ks];
    }
  }

  __syncthreads();
  if (r == 0){
    #pragma unroll
    for (int mt = 0; mt < 2; mt++)
      #pragma unroll
      for (int reg = 0; reg < 4; reg++){
        int row = mt * 16 + g * 4 + reg;
        msh[wv * 32 + row] = mrun[mt][reg];
        lsh[wv * 32 + row] = lrun[mt][reg];
      }
  }
  __syncthreads();
  #pragma unroll
  for (int mt = 0; mt < 2; mt++)
    #pragma unroll
    for (int reg = 0; reg < 4; reg++){
      int row = mt * 16 + g * 4 + reg;
      float m0v = msh[row], m1 = msh[32 + row], m2 = msh[64 + row], m3 = msh[96 + row];
      float M = fmaxf(fmaxf(m0v, m1), fmaxf(m2, m3));
      float L = lsh[row]      * __expf(m0v - M) + lsh[32 + row] * __expf(m1 - M)
              + lsh[64 + row] * __expf(m2 - M)  + lsh[96 + row] * __expf(m3 - M);
      float al = __expf(mrun[mt][reg] - M);
      if (wv == 0 && r == 0) Lsh[row] = L;
      #pragma unroll
      for (int dt = 0; dt < 4; dt++)
        Obuf[(wv * 32 + row) * 64 + dt * 16 + r] = Oa[mt][dt][reg] * al;
    }
  __syncthreads();
  {
    int row = tid >> 3;
    int dbase = (tid & 7) * 8;
    float sum[8];
    #pragma unroll
    for (int j = 0; j < 8; j++) sum[j] = 0.f;
    #pragma unroll
    for (int w4 = 0; w4 < 4; w4++){
      const float4* p = (const float4*)&Obuf[(w4 * 32 + row) * 64 + dbase];
      float4 a = p[0], b = p[1];
      sum[0] += a.x; sum[1] += a.y; sum[2] += a.z; sum[3] += a.w;
      sum[4] += b.x; sum[5] += b.y; sum[6] += b.z; sum[7] += b.w;
    }
    float invL = 1.f / Lsh[row];
    union { unsigned short u[8]; bf16x8 v; } o;
    #pragma unroll
    for (int j = 0; j < 8; j++) o.u[j] = f2bf(sum[j] * invL);
    int token = q0 + row;
    *(bf16x8*)&ao[(size_t)token * 768 + head * 64 + dbase] = o.v;
  }
}

// ---------------- proj GEMM ----------------
__global__ __launch_bounds__(256) void proj_gemm(
    const unsigned short* __restrict__ ag,   // [2304][768] bf16
    const unsigned short* __restrict__ wg,   // [768][768] bf16
    const float* __restrict__ bias,
    float* __restrict__ out)
{
  __shared__ short As[128*64];
  __shared__ short Bs[128*64];
  const int tid = threadIdx.x;
  const int lane = tid & 63;
  const int wv = tid >> 6;
  const int r = lane & 15, g = lane >> 4;
  const int wm = (wv >> 1) * 64, wn = (wv & 1) * 64;
  const int m0 = blockIdx.y * 128, n0 = blockIdx.x * 128;

  f32x4 acc[4][4];
  #pragma unroll
  for (int i = 0; i < 4; i++)
    #pragma unroll
    for (int j = 0; j < 4; j++) acc[i][j] = (f32x4){0.f, 0.f, 0.f, 0.f};

  for (int k0 = 0; k0 < 768; k0 += 64){
    __syncthreads();
    #pragma unroll
    for (int it = 0; it < 4; it++){
      int f = it * 256 + tid;
      int row = f >> 3, u = f & 7;
      int us = ((u ^ (row & 7)) << 3);
      gload_lds16(ag + (size_t)(m0 + row) * 768 + k0 + us, &As[f * 8]);
      gload_lds16(wg + (size_t)(n0 + row) * 768 + k0 + us, &Bs[f * 8]);
    }
    __syncthreads();
    #pragma unroll
    for (int ks = 0; ks < 2; ks++){
      bf16x8 af[4], bfr[4];
      #pragma unroll
      for (int mt = 0; mt < 4; mt++){
        int row = wm + mt * 16 + r;
        af[mt] = *(const bf16x8*)&As[row * 64 + ((((ks << 2) | g) ^ (r & 7)) << 3)];
      }
      #pragma unroll
      for (int nt = 0; nt < 4; nt++){
        int row = wn + nt * 16 + r;
        bfr[nt] = *(const bf16x8*)&Bs[row * 64 + ((((ks << 2) | g) ^ (r & 7)) << 3)];
      }
      #pragma unroll
      for (int mt = 0; mt < 4; mt++)
        #pragma unroll
        for (int nt = 0; nt < 4; nt++)
          acc[mt][nt] = __builtin_amdgcn_mfma_f32_16x16x32_bf16(af[mt], bfr[nt], acc[mt][nt], 0, 0, 0);
    }
  }

  #pragma unroll
  for (int mt = 0; mt < 4; mt++)
    #pragma unroll
    for (int reg = 0; reg < 4; reg++){
      int row_m = m0 + wm + mt * 16 + g * 4 + reg;
      #pragma unroll
      for (int nt = 0; nt < 4; nt++){
        int col = n0 + wn + nt * 16 + r;
        out[(size_t)row_m * 768 + col] = acc[mt][nt][reg] + bias[col];
      }
    }
}

extern "C" void kernel_launch(void* const* d_in, const int* in_sizes, int n_in,
                              void* d_out, int out_size, void* d_ws, size_t ws_size,
                              hipStream_t stream){
  (void)in_sizes; (void)n_in; (void)out_size; (void)ws_size;
  const float* x      = (const float*)d_in[0];
  const float* qkv_w  = (const float*)d_in[1];
  const float* qkv_b  = (const float*)d_in[2];
  const float* proj_w = (const float*)d_in[3];
  const float* proj_b = (const float*)d_in[4];
  const float* rph    = (const float*)d_in[5];
  const float* rpw    = (const float*)d_in[6];
  const float* Aq     = (const float*)d_in[7];
  const float* Bq     = (const float*)d_in[8];
  const float* Ak     = (const float*)d_in[9];
  const float* Bk     = (const float*)d_in[10];
  const float* Av     = (const float*)d_in[11];
  const float* Bv     = (const float*)d_in[12];

  char* w = (char*)d_ws;
  unsigned short* xb  = (unsigned short*)(w + 0);         // 2304*768 bf16 (dead after qkv_gemm)
  unsigned short* wqb = (unsigned short*)(w + 3538944);   // 2304*768 bf16
  unsigned short* wpb = (unsigned short*)(w + 7077888);   //  768*768 bf16
  unsigned short* qb  = (unsigned short*)(w + 8257536);   // 12*2304*64 bf16 (scaled)
  unsigned short* kb  = (unsigned short*)(w + 11796480);  // 12*2304*64 bf16
  unsigned short* vtb = (unsigned short*)(w + 15335424);  // 12*64*2304 bf16
  float* tb           = (float*)(w + 18874368);           // 3*2304*4 f32
  float* rhb          = (float*)(w + 18984960);           // 12*2304*48 f32
  float* rwb          = (float*)(w + 24293376);           // 12*2304*48 f32
  unsigned short* aob = (unsigned short*)(w + 29601792);  // 2304*768 bf16
  unsigned short* rphb = (unsigned short*)(w + 0);        // 95*64 bf16 (xb region)
  unsigned short* rpwb = (unsigned short*)(w + 12160);    // 95*64 bf16

  cvt_f32_bf16<<<1728, 256, 0, stream>>>(x, xb, 442368);
  cvt_f32_bf16<<<1728, 256, 0, stream>>>(qkv_w, wqb, 442368);
  cvt_f32_bf16<<<576, 256, 0, stream>>>(proj_w, wpb, 147456);
  lora_t_kernel<<<576, 256, 0, stream>>>(x, Aq, Ak, Av, tb);
  qkv_gemm<<<dim3(18, 18), 256, 0, stream>>>(xb, wqb, qkv_b, tb, Bq, Bk, Bv, qb, kb, vtb);
  cvt_f32_bf16<<<6, 256, 0, stream>>>(rph, rphb, 1520);
  cvt_f32_bf16<<<6, 256, 0, stream>>>(rpw, rpwb, 1520);
  rel_gemm<<<dim3(48, 12), 256, 0, stream>>>(qb, rphb, rpwb, rhb, rwb);
  attn_kernel<<<dim3(72, 12), 256, 0, stream>>>(qb, kb, vtb, rhb, rwb, aob);
  proj_gemm<<<dim3(6, 18), 256, 0, stream>>>(aob, wpb, proj_b, (float*)d_out);
}

// Round 6
// 176.973 us; speedup vs baseline: 2.4497x; 2.4497x over previous
//
#include <hip/hip_runtime.h>

#define NTOK 2304   // 48*48 tokens
#define NH 12
#define HD 64

typedef __attribute__((ext_vector_type(8))) short bf16x8;
typedef __attribute__((ext_vector_type(4))) float f32x4;

__device__ __forceinline__ unsigned short f2bf(float f){
  union { float f; unsigned u; } v; v.f = f;
  unsigned r = v.u + 0x7fffu + ((v.u >> 16) & 1u);
  return (unsigned short)(r >> 16);
}
__device__ __forceinline__ float bf2f(unsigned short h){
  union { unsigned u; float f; } v; v.u = ((unsigned)h) << 16;
  return v.f;
}
__device__ __forceinline__ void gload_lds16(const void* g, void* lds){
  __builtin_amdgcn_global_load_lds(
    (const __attribute__((address_space(1))) unsigned int*)g,
    (__attribute__((address_space(3))) unsigned int*)lds, 16, 0, 0);
}

// ---------------- fp32 -> bf16 convert ----------------
__global__ __launch_bounds__(256) void cvt_f32_bf16(const float* __restrict__ src,
                                                    unsigned short* __restrict__ dst, int n4){
  int i = blockIdx.x * 256 + threadIdx.x;
  if (i >= n4) return;
  float4 v = ((const float4*)src)[i];
  union { unsigned short u[4]; unsigned long long ll; } o;
  o.u[0] = f2bf(v.x); o.u[1] = f2bf(v.y); o.u[2] = f2bf(v.z); o.u[3] = f2bf(v.w);
  ((unsigned long long*)dst)[i] = o.ll;
}

// ---------------- LoRA t = x @ A^T  (t[3][2304][4]) ----------------
__global__ __launch_bounds__(256) void lora_t_kernel(const float* __restrict__ x,
    const float* __restrict__ Aq, const float* __restrict__ Ak, const float* __restrict__ Av,
    float* __restrict__ t){
  int wave = (blockIdx.x * 256 + threadIdx.x) >> 6;   // token
  int lane = threadIdx.x & 63;
  if (wave >= NTOK) return;
  const float* xr = x + (size_t)wave * 768;
  float part[12];
  #pragma unroll
  for (int j = 0; j < 12; j++) part[j] = 0.f;
  for (int k = lane; k < 768; k += 64){
    float xv = xr[k];
    #pragma unroll
    for (int r = 0; r < 4; r++){
      part[r]     += xv * Aq[r*768 + k];
      part[4 + r] += xv * Ak[r*768 + k];
      part[8 + r] += xv * Av[r*768 + k];
    }
  }
  #pragma unroll
  for (int j = 0; j < 12; j++){
    float v = part[j];
    #pragma unroll
    for (int off = 32; off; off >>= 1) v += __shfl_xor(v, off);
    if (lane == 0){
      int mat = j >> 2, r = j & 3;
      t[((size_t)mat * NTOK + wave) * 4 + r] = v;
    }
  }
}

// ---------------- fused qkv GEMM (+bias +LoRA, writes q(scaled),k,vT) ----------------
__global__ __launch_bounds__(256) void qkv_gemm(
    const unsigned short* __restrict__ xg,   // [2304][768] bf16
    const unsigned short* __restrict__ wg,   // [2304][768] bf16
    const float* __restrict__ bias,          // [2304]
    const float* __restrict__ t,             // [3][2304][4]
    const float* __restrict__ Bq, const float* __restrict__ Bk, const float* __restrict__ Bv, // [768][4]
    unsigned short* __restrict__ qo,         // [12][2304][64]  (pre-scaled by 0.125)
    unsigned short* __restrict__ ko,         // [12][2304][64]
    unsigned short* __restrict__ vT)         // [12][64][2304]
{
  __shared__ short As[128*64];
  __shared__ short Bs[128*64];
  const int tid = threadIdx.x;
  const int lane = tid & 63;
  const int wv = tid >> 6;
  const int r = lane & 15, g = lane >> 4;
  const int wm = (wv >> 1) * 64, wn = (wv & 1) * 64;
  const int m0 = blockIdx.y * 128, n0 = blockIdx.x * 128;

  f32x4 acc[4][4];
  #pragma unroll
  for (int i = 0; i < 4; i++)
    #pragma unroll
    for (int j = 0; j < 4; j++) acc[i][j] = (f32x4){0.f, 0.f, 0.f, 0.f};

  for (int k0 = 0; k0 < 768; k0 += 64){
    __syncthreads();
    #pragma unroll
    for (int it = 0; it < 4; it++){
      int f = it * 256 + tid;
      int row = f >> 3, u = f & 7;
      int us = ((u ^ (row & 7)) << 3);
      gload_lds16(xg + (size_t)(m0 + row) * 768 + k0 + us, &As[f * 8]);
      gload_lds16(wg + (size_t)(n0 + row) * 768 + k0 + us, &Bs[f * 8]);
    }
    __syncthreads();
    #pragma unroll
    for (int ks = 0; ks < 2; ks++){
      bf16x8 af[4], bfr[4];
      #pragma unroll
      for (int mt = 0; mt < 4; mt++){
        int row = wm + mt * 16 + r;
        af[mt] = *(const bf16x8*)&As[row * 64 + ((((ks << 2) | g) ^ (r & 7)) << 3)];
      }
      #pragma unroll
      for (int nt = 0; nt < 4; nt++){
        int row = wn + nt * 16 + r;
        bfr[nt] = *(const bf16x8*)&Bs[row * 64 + ((((ks << 2) | g) ^ (r & 7)) << 3)];
      }
      #pragma unroll
      for (int mt = 0; mt < 4; mt++)
        #pragma unroll
        for (int nt = 0; nt < 4; nt++)
          acc[mt][nt] = __builtin_amdgcn_mfma_f32_16x16x32_bf16(af[mt], bfr[nt], acc[mt][nt], 0, 0, 0);
    }
  }

  const int part = n0 / 768;
  const float* Bl = (part == 0) ? Bq : ((part == 1) ? Bk : Bv);
  const float* tp = t + (size_t)part * NTOK * 4;
  #pragma unroll
  for (int mt = 0; mt < 4; mt++){
    #pragma unroll
    for (int reg = 0; reg < 4; reg++){
      int row_m = m0 + wm + mt * 16 + g * 4 + reg;
      float4 tv = *(const float4*)&tp[row_m * 4];
      #pragma unroll
      for (int nt = 0; nt < 4; nt++){
        int col = n0 + wn + nt * 16 + r;
        int cc = col - part * 768;
        float4 bw = *(const float4*)&Bl[cc * 4];
        float val = acc[mt][nt][reg] + bias[col]
                  + 0.25f * (tv.x * bw.x + tv.y * bw.y + tv.z * bw.z + tv.w * bw.w);
        int head = cc >> 6, d = cc & 63;
        if (part == 0)      qo[((size_t)head * NTOK + row_m) * 64 + d] = f2bf(val * 0.125f);
        else if (part == 1) ko[((size_t)head * NTOK + row_m) * 64 + d] = f2bf(val);
        else                vT[((size_t)head * 64 + d) * NTOK + row_m] = f2bf(val);
      }
    }
  }
}

// ---------------- rel_h / rel_w via MFMA ----------------
__global__ __launch_bounds__(256, 2) void rel_gemm(
    const unsigned short* __restrict__ qg,    // [12][2304][64] bf16 (scaled by 0.125)
    const unsigned short* __restrict__ rphb,  // [95][64] bf16
    const unsigned short* __restrict__ rpwb,  // [95][64] bf16
    float* __restrict__ rel_h,                // [12][2304][48]
    float* __restrict__ rel_w)                // [12][2304][48]
{
  __shared__ float G[48 * 196];
  const int ih = blockIdx.x, head = blockIdx.y;
  const int tid = threadIdx.x, lane = tid & 63, wv = tid >> 6;
  const int r = lane & 15, g = lane >> 4;
  const int q0 = ih * 48;

  bf16x8 af[3][2];
  #pragma unroll
  for (int mt = 0; mt < 3; mt++)
    #pragma unroll
    for (int ks = 0; ks < 2; ks++)
      af[mt][ks] = *(const bf16x8*)&qg[((size_t)head * NTOK + q0 + mt * 16 + r) * 64 + ks * 32 + g * 8];

  bf16x8 bf[3][2];
  #pragma unroll
  for (int nt = 0; nt < 3; nt++){
    int col = wv * 48 + nt * 16 + r;
    const unsigned short* src = (col < 95) ? &rphb[(size_t)col * 64]
                              : (col < 190) ? &rpwb[(size_t)(col - 95) * 64]
                              : &rpwb[0];
    #pragma unroll
    for (int ks = 0; ks < 2; ks++)
      bf[nt][ks] = *(const bf16x8*)&src[ks * 32 + g * 8];
  }

  f32x4 acc[3][3];
  #pragma unroll
  for (int mt = 0; mt < 3; mt++)
    #pragma unroll
    for (int nt = 0; nt < 3; nt++) acc[mt][nt] = (f32x4){0.f, 0.f, 0.f, 0.f};
  #pragma unroll
  for (int ks = 0; ks < 2; ks++)
    #pragma unroll
    for (int mt = 0; mt < 3; mt++)
      #pragma unroll
      for (int nt = 0; nt < 3; nt++)
        acc[mt][nt] = __builtin_amdgcn_mfma_f32_16x16x32_bf16(af[mt][ks], bf[nt][ks], acc[mt][nt], 0, 0, 0);

  #pragma unroll
  for (int mt = 0; mt < 3; mt++)
    #pragma unroll
    for (int reg = 0; reg < 4; reg++){
      int row = mt * 16 + g * 4 + reg;
      #pragma unroll
      for (int nt = 0; nt < 3; nt++)
        G[row * 196 + wv * 48 + nt * 16 + r] = acc[mt][nt][reg];
    }
  __syncthreads();

  for (int idx = tid; idx < 48 * 96; idx += 256){
    int i = idx / 96, c = idx % 96;
    size_t gi = (size_t)head * NTOK + q0 + i;
    if (c < 48) rel_h[gi * 48 + c]        = G[i * 196 + (ih + 47 - c)] * 8.f;
    else        rel_w[gi * 48 + (c - 48)] = G[i * 196 + 95 + (i + 47 - (c - 48))] * 8.f;
  }
}

// ---------------- flash attention v5 ----------------
// 32 q-rows/block, 4 waves split KV. Swapped QK^T (mfma(K,Q)), no-max softmax
// (|S+bias| < ~3 by construction), structural bias indexing:
//   kw = ((it+nt)%3)*16 + g*4+reg   (static after unroll-by-3)
//   kh = 12*wv + 4*it3 + itn + hi(itn,nt)   (lane-uniform broadcast)
// P packed via v_cvt_pk_bf16_f32 -> ds_write_b64.
__global__ __launch_bounds__(256, 2) void attn_kernel(
    const unsigned short* __restrict__ qg,   // [12][2304][64] scaled
    const unsigned short* __restrict__ kg,   // [12][2304][64]
    const unsigned short* __restrict__ vT,   // [12][64][2304]
    const float* __restrict__ rel_h,         // [12][2304][48]
    const float* __restrict__ rel_w,         // [12][2304][48]
    unsigned short* __restrict__ ao)         // [2304][768]
{
  __shared__ __align__(16) char smem[32768 + 512];
  float* rel_s = (float*)smem;                              // [32][100]
  unsigned short* P_lds = (unsigned short*)(smem + 12800);  // [4][32][72]
  float* Obuf = (float*)smem;                               // [4][32][64] (aliases)
  float* lsh  = (float*)(smem + 32768);                     // [4][32]

  const int head = blockIdx.y;
  const int q0 = blockIdx.x * 32;
  const int tid = threadIdx.x, lane = tid & 63, wv = tid >> 6;
  const int r = lane & 15, g = lane >> 4;

  for (int idx = tid; idx < 32 * 96; idx += 256){
    int i = idx / 96, c = idx % 96;
    int token = head * NTOK + q0 + i;
    rel_s[i * 100 + c] = (c < 48) ? rel_h[(size_t)token * 48 + c]
                                  : rel_w[(size_t)token * 48 + (c - 48)];
  }
  __syncthreads();

  bf16x8 qf[2][2];
  #pragma unroll
  for (int mt = 0; mt < 2; mt++)
    #pragma unroll
    for (int ks = 0; ks < 2; ks++)
      qf[mt][ks] = *(const bf16x8*)&qg[((size_t)head * NTOK + q0 + mt * 16 + r) * 64 + ks * 32 + g * 8];

  f32x4 Oa[2][4];
  float lrun[2] = {0.f, 0.f};
  #pragma unroll
  for (int mt = 0; mt < 2; mt++)
    #pragma unroll
    for (int dt = 0; dt < 4; dt++) Oa[mt][dt] = (f32x4){0.f, 0.f, 0.f, 0.f};

  unsigned short* pbase = &P_lds[wv * 32 * 72];
  const unsigned short* kbase = kg + (size_t)head * NTOK * 64;
  const unsigned short* vbase = vT + (size_t)head * 64 * NTOK;
  const int key_base = wv * 9 * 64;

  // hi(itn,nt): kh = khb + hi ; mj(itn,nt) = (itn+nt)%3
  const int HI_T[3][4] = {{0,0,0,1},{0,0,1,1},{0,1,1,1}};
  const int MJ_T[3][4] = {{0,1,2,0},{1,2,0,1},{2,0,1,2}};

  bf16x8 kc[4][2], kn[4][2];
  #pragma unroll
  for (int nt = 0; nt < 4; nt++)
    #pragma unroll
    for (int ks = 0; ks < 2; ks++)
      kc[nt][ks] = *(const bf16x8*)&kbase[(size_t)(key_base + nt * 16 + r) * 64 + ks * 32 + g * 8];

  for (int it3 = 0; it3 < 3; it3++){
    #pragma unroll
    for (int itn = 0; itn < 3; itn++){
      const int it = it3 * 3 + itn;
      const int key0 = key_base + it * 64;

      // hoist V loads (consumed after softmax)
      bf16x8 vf[4][2];
      #pragma unroll
      for (int dt = 0; dt < 4; dt++)
        #pragma unroll
        for (int ks = 0; ks < 2; ks++)
          vf[dt][ks] = *(const bf16x8*)&vbase[(size_t)(dt * 16 + r) * NTOK + key0 + ks * 32 + g * 8];

      // prefetch next K tile
      if (it < 8){
        #pragma unroll
        for (int nt = 0; nt < 4; nt++)
          #pragma unroll
          for (int ks = 0; ks < 2; ks++)
            kn[nt][ks] = *(const bf16x8*)&kbase[(size_t)(key0 + 64 + nt * 16 + r) * 64 + ks * 32 + g * 8];
      }

      // lane-uniform rel_h pair for this iteration
      const int khb = 12 * wv + 4 * it3 + itn;
      float bh0[2], bh1[2];
      #pragma unroll
      for (int mt = 0; mt < 2; mt++){
        const float* rs = &rel_s[(mt * 16 + r) * 100];
        bh0[mt] = rs[khb]; bh1[mt] = rs[khb + 1];
      }

      // two key-halves: QK^T (swapped) -> bias -> exp -> pack -> P_lds
      #pragma unroll
      for (int hf = 0; hf < 2; hf++){
        f32x4 s[2][2];
        #pragma unroll
        for (int ntl = 0; ntl < 2; ntl++)
          #pragma unroll
          for (int mt = 0; mt < 2; mt++) s[ntl][mt] = (f32x4){0.f, 0.f, 0.f, 0.f};
        #pragma unroll
        for (int ntl = 0; ntl < 2; ntl++)
          #pragma unroll
          for (int mt = 0; mt < 2; mt++){
            s[ntl][mt] = __builtin_amdgcn_mfma_f32_16x16x32_bf16(kc[hf*2+ntl][0], qf[mt][0], s[ntl][mt], 0, 0, 0);
            s[ntl][mt] = __builtin_amdgcn_mfma_f32_16x16x32_bf16(kc[hf*2+ntl][1], qf[mt][1], s[ntl][mt], 0, 0, 0);
          }
        #pragma unroll
        for (int ntl = 0; ntl < 2; ntl++){
          const int nt = hf * 2 + ntl;
          const int j  = MJ_T[itn][nt];
          const int hi = HI_T[itn][nt];
          #pragma unroll
          for (int mt = 0; mt < 2; mt++){
            const float* rs = &rel_s[(mt * 16 + r) * 100];
            float4 w = *(const float4*)&rs[48 + j * 16 + g * 4];
            float bh = hi ? bh1[mt] : bh0[mt];
            float p0 = __expf(s[ntl][mt][0] + bh + w.x);
            float p1 = __expf(s[ntl][mt][1] + bh + w.y);
            float p2 = __expf(s[ntl][mt][2] + bh + w.z);
            float p3 = __expf(s[ntl][mt][3] + bh + w.w);
            lrun[mt] += (p0 + p1) + (p2 + p3);
            unsigned plo, phi;
            asm("v_cvt_pk_bf16_f32 %0, %1, %2" : "=v"(plo) : "v"(p0), "v"(p1));
            asm("v_cvt_pk_bf16_f32 %0, %1, %2" : "=v"(phi) : "v"(p2), "v"(p3));
            unsigned long long pk = ((unsigned long long)phi << 32) | plo;
            *(unsigned long long*)&pbase[(mt * 16 + r) * 72 + nt * 16 + g * 4] = pk;
          }
        }
      }

      // P A-frag read + PV
      bf16x8 pf[2][2];
      #pragma unroll
      for (int mt = 0; mt < 2; mt++)
        #pragma unroll
        for (int ks = 0; ks < 2; ks++)
          pf[mt][ks] = *(const bf16x8*)&pbase[(mt * 16 + r) * 72 + ks * 32 + g * 8];
      #pragma unroll
      for (int dt = 0; dt < 4; dt++)
        #pragma unroll
        for (int ks = 0; ks < 2; ks++)
          #pragma unroll
          for (int mt = 0; mt < 2; mt++)
            Oa[mt][dt] = __builtin_amdgcn_mfma_f32_16x16x32_bf16(pf[mt][ks], vf[dt][ks], Oa[mt][dt], 0, 0, 0);

      if (it < 8){
        #pragma unroll
        for (int nt = 0; nt < 4; nt++)
          #pragma unroll
          for (int ks = 0; ks < 2; ks++)
            kc[nt][ks] = kn[nt][ks];
      }
    }
  }

  // per-wave row-sums: reduce lrun over g (keys split across g,reg,nt; q = mt*16+r)
  #pragma unroll
  for (int mt = 0; mt < 2; mt++){
    float l = lrun[mt];
    l += __shfl_xor(l, 16);
    l += __shfl_xor(l, 32);
    if (g == 0) lsh[wv * 32 + mt * 16 + r] = l;
  }
  __syncthreads();   // all waves done with rel_s/P_lds; lsh populated

  #pragma unroll
  for (int mt = 0; mt < 2; mt++)
    #pragma unroll
    for (int reg = 0; reg < 4; reg++){
      int row = mt * 16 + g * 4 + reg;
      #pragma unroll
      for (int dt = 0; dt < 4; dt++)
        Obuf[(wv * 32 + row) * 64 + dt * 16 + r] = Oa[mt][dt][reg];
    }
  __syncthreads();
  {
    int row = tid >> 3;
    int dbase = (tid & 7) * 8;
    float sum[8];
    #pragma unroll
    for (int j = 0; j < 8; j++) sum[j] = 0.f;
    #pragma unroll
    for (int w4 = 0; w4 < 4; w4++){
      const float4* p = (const float4*)&Obuf[(w4 * 32 + row) * 64 + dbase];
      float4 a = p[0], b = p[1];
      sum[0] += a.x; sum[1] += a.y; sum[2] += a.z; sum[3] += a.w;
      sum[4] += b.x; sum[5] += b.y; sum[6] += b.z; sum[7] += b.w;
    }
    float L = lsh[row] + lsh[32 + row] + lsh[64 + row] + lsh[96 + row];
    float invL = 1.f / L;
    union { unsigned short u[8]; bf16x8 v; } o;
    #pragma unroll
    for (int j = 0; j < 8; j++) o.u[j] = f2bf(sum[j] * invL);
    int token = q0 + row;
    *(bf16x8*)&ao[(size_t)token * 768 + head * 64 + dbase] = o.v;
  }
}

// ---------------- proj GEMM ----------------
__global__ __launch_bounds__(256) void proj_gemm(
    const unsigned short* __restrict__ ag,   // [2304][768] bf16
    const unsigned short* __restrict__ wg,   // [768][768] bf16
    const float* __restrict__ bias,
    float* __restrict__ out)
{
  __shared__ short As[128*64];
  __shared__ short Bs[128*64];
  const int tid = threadIdx.x;
  const int lane = tid & 63;
  const int wv = tid >> 6;
  const int r = lane & 15, g = lane >> 4;
  const int wm = (wv >> 1) * 64, wn = (wv & 1) * 64;
  const int m0 = blockIdx.y * 128, n0 = blockIdx.x * 128;

  f32x4 acc[4][4];
  #pragma unroll
  for (int i = 0; i < 4; i++)
    #pragma unroll
    for (int j = 0; j < 4; j++) acc[i][j] = (f32x4){0.f, 0.f, 0.f, 0.f};

  for (int k0 = 0; k0 < 768; k0 += 64){
    __syncthreads();
    #pragma unroll
    for (int it = 0; it < 4; it++){
      int f = it * 256 + tid;
      int row = f >> 3, u = f & 7;
      int us = ((u ^ (row & 7)) << 3);
      gload_lds16(ag + (size_t)(m0 + row) * 768 + k0 + us, &As[f * 8]);
      gload_lds16(wg + (size_t)(n0 + row) * 768 + k0 + us, &Bs[f * 8]);
    }
    __syncthreads();
    #pragma unroll
    for (int ks = 0; ks < 2; ks++){
      bf16x8 af[4], bfr[4];
      #pragma unroll
      for (int mt = 0; mt < 4; mt++){
        int row = wm + mt * 16 + r;
        af[mt] = *(const bf16x8*)&As[row * 64 + ((((ks << 2) | g) ^ (r & 7)) << 3)];
      }
      #pragma unroll
      for (int nt = 0; nt < 4; nt++){
        int row = wn + nt * 16 + r;
        bfr[nt] = *(const bf16x8*)&Bs[row * 64 + ((((ks << 2) | g) ^ (r & 7)) << 3)];
      }
      #pragma unroll
      for (int mt = 0; mt < 4; mt++)
        #pragma unroll
        for (int nt = 0; nt < 4; nt++)
          acc[mt][nt] = __builtin_amdgcn_mfma_f32_16x16x32_bf16(af[mt], bfr[nt], acc[mt][nt], 0, 0, 0);
    }
  }

  #pragma unroll
  for (int mt = 0; mt < 4; mt++)
    #pragma unroll
    for (int reg = 0; reg < 4; reg++){
      int row_m = m0 + wm + mt * 16 + g * 4 + reg;
      #pragma unroll
      for (int nt = 0; nt < 4; nt++){
        int col = n0 + wn + nt * 16 + r;
        out[(size_t)row_m * 768 + col] = acc[mt][nt][reg] + bias[col];
      }
    }
}

extern "C" void kernel_launch(void* const* d_in, const int* in_sizes, int n_in,
                              void* d_out, int out_size, void* d_ws, size_t ws_size,
                              hipStream_t stream){
  (void)in_sizes; (void)n_in; (void)out_size; (void)ws_size;
  const float* x      = (const float*)d_in[0];
  const float* qkv_w  = (const float*)d_in[1];
  const float* qkv_b  = (const float*)d_in[2];
  const float* proj_w = (const float*)d_in[3];
  const float* proj_b = (const float*)d_in[4];
  const float* rph    = (const float*)d_in[5];
  const float* rpw    = (const float*)d_in[6];
  const float* Aq     = (const float*)d_in[7];
  const float* Bq     = (const float*)d_in[8];
  const float* Ak     = (const float*)d_in[9];
  const float* Bk     = (const float*)d_in[10];
  const float* Av     = (const float*)d_in[11];
  const float* Bv     = (const float*)d_in[12];

  char* w = (char*)d_ws;
  unsigned short* xb  = (unsigned short*)(w + 0);         // 2304*768 bf16 (dead after qkv_gemm)
  unsigned short* wqb = (unsigned short*)(w + 3538944);   // 2304*768 bf16
  unsigned short* wpb = (unsigned short*)(w + 7077888);   //  768*768 bf16
  unsigned short* qb  = (unsigned short*)(w + 8257536);   // 12*2304*64 bf16 (scaled)
  unsigned short* kb  = (unsigned short*)(w + 11796480);  // 12*2304*64 bf16
  unsigned short* vtb = (unsigned short*)(w + 15335424);  // 12*64*2304 bf16
  float* tb           = (float*)(w + 18874368);           // 3*2304*4 f32
  float* rhb          = (float*)(w + 18984960);           // 12*2304*48 f32
  float* rwb          = (float*)(w + 24293376);           // 12*2304*48 f32
  unsigned short* aob = (unsigned short*)(w + 29601792);  // 2304*768 bf16
  unsigned short* rphb = (unsigned short*)(w + 0);        // 95*64 bf16 (xb region)
  unsigned short* rpwb = (unsigned short*)(w + 12160);    // 95*64 bf16

  cvt_f32_bf16<<<1728, 256, 0, stream>>>(x, xb, 442368);
  cvt_f32_bf16<<<1728, 256, 0, stream>>>(qkv_w, wqb, 442368);
  cvt_f32_bf16<<<576, 256, 0, stream>>>(proj_w, wpb, 147456);
  lora_t_kernel<<<576, 256, 0, stream>>>(x, Aq, Ak, Av, tb);
  qkv_gemm<<<dim3(18, 18), 256, 0, stream>>>(xb, wqb, qkv_b, tb, Bq, Bk, Bv, qb, kb, vtb);
  cvt_f32_bf16<<<6, 256, 0, stream>>>(rph, rphb, 1520);
  cvt_f32_bf16<<<6, 256, 0, stream>>>(rpw, rpwb, 1520);
  rel_gemm<<<dim3(48, 12), 256, 0, stream>>>(qb, rphb, rpwb, rhb, rwb);
  attn_kernel<<<dim3(72, 12), 256, 0, stream>>>(qb, kb, vtb, rhb, rwb, aob);
  proj_gemm<<<dim3(6, 18), 256, 0, stream>>>(aob, wpb, proj_b, (float*)d_out);
}

// Round 7
// 164.293 us; speedup vs baseline: 2.6387x; 1.0772x over previous
//
#include <hip/hip_runtime.h>

#define NTOK 2304   // 48*48 tokens
#define NH 12
#define HD 64

typedef __attribute__((ext_vector_type(8))) short bf16x8;
typedef __attribute__((ext_vector_type(4))) float f32x4;

__device__ __forceinline__ unsigned short f2bf(float f){
  union { float f; unsigned u; } v; v.f = f;
  unsigned r = v.u + 0x7fffu + ((v.u >> 16) & 1u);
  return (unsigned short)(r >> 16);
}
__device__ __forceinline__ float bf2f(unsigned short h){
  union { unsigned u; float f; } v; v.u = ((unsigned)h) << 16;
  return v.f;
}
__device__ __forceinline__ void gload_lds16(const void* g, void* lds){
  __builtin_amdgcn_global_load_lds(
    (const __attribute__((address_space(1))) unsigned int*)g,
    (__attribute__((address_space(3))) unsigned int*)lds, 16, 0, 0);
}

// ---------------- fp32 -> bf16 convert ----------------
__global__ __launch_bounds__(256) void cvt_f32_bf16(const float* __restrict__ src,
                                                    unsigned short* __restrict__ dst, int n4){
  int i = blockIdx.x * 256 + threadIdx.x;
  if (i >= n4) return;
  float4 v = ((const float4*)src)[i];
  union { unsigned short u[4]; unsigned long long ll; } o;
  o.u[0] = f2bf(v.x); o.u[1] = f2bf(v.y); o.u[2] = f2bf(v.z); o.u[3] = f2bf(v.w);
  ((unsigned long long*)dst)[i] = o.ll;
}

// ---------------- LoRA t = x @ A^T  (t[3][2304][4]) ----------------
__global__ __launch_bounds__(256) void lora_t_kernel(const float* __restrict__ x,
    const float* __restrict__ Aq, const float* __restrict__ Ak, const float* __restrict__ Av,
    float* __restrict__ t){
  int wave = (blockIdx.x * 256 + threadIdx.x) >> 6;   // token
  int lane = threadIdx.x & 63;
  if (wave >= NTOK) return;
  const float* xr = x + (size_t)wave * 768;
  float part[12];
  #pragma unroll
  for (int j = 0; j < 12; j++) part[j] = 0.f;
  for (int k = lane; k < 768; k += 64){
    float xv = xr[k];
    #pragma unroll
    for (int r = 0; r < 4; r++){
      part[r]     += xv * Aq[r*768 + k];
      part[4 + r] += xv * Ak[r*768 + k];
      part[8 + r] += xv * Av[r*768 + k];
    }
  }
  #pragma unroll
  for (int j = 0; j < 12; j++){
    float v = part[j];
    #pragma unroll
    for (int off = 32; off; off >>= 1) v += __shfl_xor(v, off);
    if (lane == 0){
      int mat = j >> 2, r = j & 3;
      t[((size_t)mat * NTOK + wave) * 4 + r] = v;
    }
  }
}

// ---------------- fused qkv GEMM (+bias +LoRA, writes q(scaled),k,vT) ----------------
__global__ __launch_bounds__(256) void qkv_gemm(
    const unsigned short* __restrict__ xg,   // [2304][768] bf16
    const unsigned short* __restrict__ wg,   // [2304][768] bf16
    const float* __restrict__ bias,          // [2304]
    const float* __restrict__ t,             // [3][2304][4]
    const float* __restrict__ Bq, const float* __restrict__ Bk, const float* __restrict__ Bv, // [768][4]
    unsigned short* __restrict__ qo,         // [12][2304][64]  (pre-scaled by 0.125)
    unsigned short* __restrict__ ko,         // [12][2304][64]
    unsigned short* __restrict__ vT)         // [12][64][2304]
{
  __shared__ short As[128*64];
  __shared__ short Bs[128*64];
  const int tid = threadIdx.x;
  const int lane = tid & 63;
  const int wv = tid >> 6;
  const int r = lane & 15, g = lane >> 4;
  const int wm = (wv >> 1) * 64, wn = (wv & 1) * 64;
  const int m0 = blockIdx.y * 128, n0 = blockIdx.x * 128;

  f32x4 acc[4][4];
  #pragma unroll
  for (int i = 0; i < 4; i++)
    #pragma unroll
    for (int j = 0; j < 4; j++) acc[i][j] = (f32x4){0.f, 0.f, 0.f, 0.f};

  for (int k0 = 0; k0 < 768; k0 += 64){
    __syncthreads();
    #pragma unroll
    for (int it = 0; it < 4; it++){
      int f = it * 256 + tid;
      int row = f >> 3, u = f & 7;
      int us = ((u ^ (row & 7)) << 3);
      gload_lds16(xg + (size_t)(m0 + row) * 768 + k0 + us, &As[f * 8]);
      gload_lds16(wg + (size_t)(n0 + row) * 768 + k0 + us, &Bs[f * 8]);
    }
    __syncthreads();
    #pragma unroll
    for (int ks = 0; ks < 2; ks++){
      bf16x8 af[4], bfr[4];
      #pragma unroll
      for (int mt = 0; mt < 4; mt++){
        int row = wm + mt * 16 + r;
        af[mt] = *(const bf16x8*)&As[row * 64 + ((((ks << 2) | g) ^ (r & 7)) << 3)];
      }
      #pragma unroll
      for (int nt = 0; nt < 4; nt++){
        int row = wn + nt * 16 + r;
        bfr[nt] = *(const bf16x8*)&Bs[row * 64 + ((((ks << 2) | g) ^ (r & 7)) << 3)];
      }
      #pragma unroll
      for (int mt = 0; mt < 4; mt++)
        #pragma unroll
        for (int nt = 0; nt < 4; nt++)
          acc[mt][nt] = __builtin_amdgcn_mfma_f32_16x16x32_bf16(af[mt], bfr[nt], acc[mt][nt], 0, 0, 0);
    }
  }

  const int part = n0 / 768;
  const float* Bl = (part == 0) ? Bq : ((part == 1) ? Bk : Bv);
  const float* tp = t + (size_t)part * NTOK * 4;
  #pragma unroll
  for (int mt = 0; mt < 4; mt++){
    #pragma unroll
    for (int reg = 0; reg < 4; reg++){
      int row_m = m0 + wm + mt * 16 + g * 4 + reg;
      float4 tv = *(const float4*)&tp[row_m * 4];
      #pragma unroll
      for (int nt = 0; nt < 4; nt++){
        int col = n0 + wn + nt * 16 + r;
        int cc = col - part * 768;
        float4 bw = *(const float4*)&Bl[cc * 4];
        float val = acc[mt][nt][reg] + bias[col]
                  + 0.25f * (tv.x * bw.x + tv.y * bw.y + tv.z * bw.z + tv.w * bw.w);
        int head = cc >> 6, d = cc & 63;
        if (part == 0)      qo[((size_t)head * NTOK + row_m) * 64 + d] = f2bf(val * 0.125f);
        else if (part == 1) ko[((size_t)head * NTOK + row_m) * 64 + d] = f2bf(val);
        else                vT[((size_t)head * 64 + d) * NTOK + row_m] = f2bf(val);
      }
    }
  }
}

// ---------------- rel_h / rel_w via MFMA ----------------
__global__ __launch_bounds__(256, 2) void rel_gemm(
    const unsigned short* __restrict__ qg,    // [12][2304][64] bf16 (scaled by 0.125)
    const unsigned short* __restrict__ rphb,  // [95][64] bf16
    const unsigned short* __restrict__ rpwb,  // [95][64] bf16
    float* __restrict__ rel_h,                // [12][2304][48]
    float* __restrict__ rel_w)                // [12][2304][48]
{
  __shared__ float G[48 * 196];
  const int ih = blockIdx.x, head = blockIdx.y;
  const int tid = threadIdx.x, lane = tid & 63, wv = tid >> 6;
  const int r = lane & 15, g = lane >> 4;
  const int q0 = ih * 48;

  bf16x8 af[3][2];
  #pragma unroll
  for (int mt = 0; mt < 3; mt++)
    #pragma unroll
    for (int ks = 0; ks < 2; ks++)
      af[mt][ks] = *(const bf16x8*)&qg[((size_t)head * NTOK + q0 + mt * 16 + r) * 64 + ks * 32 + g * 8];

  bf16x8 bf[3][2];
  #pragma unroll
  for (int nt = 0; nt < 3; nt++){
    int col = wv * 48 + nt * 16 + r;
    const unsigned short* src = (col < 95) ? &rphb[(size_t)col * 64]
                              : (col < 190) ? &rpwb[(size_t)(col - 95) * 64]
                              : &rpwb[0];
    #pragma unroll
    for (int ks = 0; ks < 2; ks++)
      bf[nt][ks] = *(const bf16x8*)&src[ks * 32 + g * 8];
  }

  f32x4 acc[3][3];
  #pragma unroll
  for (int mt = 0; mt < 3; mt++)
    #pragma unroll
    for (int nt = 0; nt < 3; nt++) acc[mt][nt] = (f32x4){0.f, 0.f, 0.f, 0.f};
  #pragma unroll
  for (int ks = 0; ks < 2; ks++)
    #pragma unroll
    for (int mt = 0; mt < 3; mt++)
      #pragma unroll
      for (int nt = 0; nt < 3; nt++)
        acc[mt][nt] = __builtin_amdgcn_mfma_f32_16x16x32_bf16(af[mt][ks], bf[nt][ks], acc[mt][nt], 0, 0, 0);

  #pragma unroll
  for (int mt = 0; mt < 3; mt++)
    #pragma unroll
    for (int reg = 0; reg < 4; reg++){
      int row = mt * 16 + g * 4 + reg;
      #pragma unroll
      for (int nt = 0; nt < 3; nt++)
        G[row * 196 + wv * 48 + nt * 16 + r] = acc[mt][nt][reg];
    }
  __syncthreads();

  for (int idx = tid; idx < 48 * 96; idx += 256){
    int i = idx / 96, c = idx % 96;
    size_t gi = (size_t)head * NTOK + q0 + i;
    if (c < 48) rel_h[gi * 48 + c]        = G[i * 196 + (ih + 47 - c)] * 8.f;
    else        rel_w[gi * 48 + (c - 48)] = G[i * 196 + 95 + (i + 47 - (c - 48))] * 8.f;
  }
}

// ---------------- flash attention v6 ----------------
// 32 q-rows/block, 4 waves split KV (576 keys each, 18 tiles of 32 keys).
// Register-slim for 4 blocks/CU: arch ~55 (cap 64) + acc 48 (cap 64).
// Swapped QK^T, no-max softmax, structural bias:
//   key = wv*576 + 16e + g*4+reg, e=2it+ntl -> kh = 12wv + floor(e/3) (uniform),
//   kw = 16*(e%3) + g*4+reg (float4 read), never straddles 48-boundary.
__global__ __launch_bounds__(256, 4) void attn_kernel(
    const unsigned short* __restrict__ qg,   // [12][2304][64] scaled
    const unsigned short* __restrict__ kg,   // [12][2304][64]
    const unsigned short* __restrict__ vT,   // [12][64][2304]
    const float* __restrict__ rel_h,         // [12][2304][48]
    const float* __restrict__ rel_w,         // [12][2304][48]
    unsigned short* __restrict__ ao)         // [2304][768]
{
  __shared__ __align__(16) char smem[32768 + 512];
  float* rel_s = (float*)smem;                              // [32][100]
  unsigned short* P_lds = (unsigned short*)(smem + 12800);  // [4][32][40]
  float* Obuf = (float*)smem;                               // [4][32][64] (aliases)
  float* lsh  = (float*)(smem + 32768);                     // [4][32]

  const int head = blockIdx.y;
  const int q0 = blockIdx.x * 32;
  const int tid = threadIdx.x, lane = tid & 63, wv = tid >> 6;
  const int r = lane & 15, g = lane >> 4;

  for (int idx = tid; idx < 32 * 96; idx += 256){
    int i = idx / 96, c = idx % 96;
    int token = head * NTOK + q0 + i;
    rel_s[i * 100 + c] = (c < 48) ? rel_h[(size_t)token * 48 + c]
                                  : rel_w[(size_t)token * 48 + (c - 48)];
  }
  __syncthreads();

  bf16x8 qf[2][2];
  #pragma unroll
  for (int mt = 0; mt < 2; mt++)
    #pragma unroll
    for (int ks = 0; ks < 2; ks++)
      qf[mt][ks] = *(const bf16x8*)&qg[((size_t)head * NTOK + q0 + mt * 16 + r) * 64 + ks * 32 + g * 8];

  f32x4 Oa[2][4];
  float lrun[2] = {0.f, 0.f};
  #pragma unroll
  for (int mt = 0; mt < 2; mt++)
    #pragma unroll
    for (int dt = 0; dt < 4; dt++) Oa[mt][dt] = (f32x4){0.f, 0.f, 0.f, 0.f};

  unsigned short* pbase = &P_lds[wv * 32 * 40];
  const unsigned short* kbase = kg + (size_t)head * NTOK * 64;
  const unsigned short* vbase = vT + (size_t)head * 64 * NTOK;
  const int key_base = wv * 576;

  // e = 2*it+ntl, it = 3a+b:  kh = 12wv + 2a + HI[b][ntl], j = J[b][ntl]
  const int HI_T[3][2] = {{0,0},{0,1},{1,1}};
  const int MJ_T[3][2] = {{0,1},{2,0},{1,2}};

  for (int a = 0; a < 6; a++){
    #pragma unroll
    for (int b = 0; b < 3; b++){
      const int it = a * 3 + b;
      const int key0 = key_base + it * 32;

      // K fragments (32 keys), loaded fresh each iter (TLP hides latency)
      bf16x8 kc[2][2];
      #pragma unroll
      for (int ntl = 0; ntl < 2; ntl++)
        #pragma unroll
        for (int ks = 0; ks < 2; ks++)
          kc[ntl][ks] = *(const bf16x8*)&kbase[(size_t)(key0 + ntl * 16 + r) * 64 + ks * 32 + g * 8];

      // QK^T (swapped): s[ntl][mt], D col = q (r), rows = keys (g*4+reg)
      f32x4 s[2][2];
      #pragma unroll
      for (int ntl = 0; ntl < 2; ntl++)
        #pragma unroll
        for (int mt = 0; mt < 2; mt++){
          s[ntl][mt] = (f32x4){0.f, 0.f, 0.f, 0.f};
          s[ntl][mt] = __builtin_amdgcn_mfma_f32_16x16x32_bf16(kc[ntl][0], qf[mt][0], s[ntl][mt], 0, 0, 0);
          s[ntl][mt] = __builtin_amdgcn_mfma_f32_16x16x32_bf16(kc[ntl][1], qf[mt][1], s[ntl][mt], 0, 0, 0);
        }

      // bias + exp + pack -> P_lds
      #pragma unroll
      for (int ntl = 0; ntl < 2; ntl++){
        const int j  = MJ_T[b][ntl];
        const int kh = 12 * wv + 2 * a + HI_T[b][ntl];
        #pragma unroll
        for (int mt = 0; mt < 2; mt++){
          const float* rs = &rel_s[(mt * 16 + r) * 100];
          float bh = rs[kh];
          float4 w = *(const float4*)&rs[48 + j * 16 + g * 4];
          float p0 = __expf(s[ntl][mt][0] + bh + w.x);
          float p1 = __expf(s[ntl][mt][1] + bh + w.y);
          float p2 = __expf(s[ntl][mt][2] + bh + w.z);
          float p3 = __expf(s[ntl][mt][3] + bh + w.w);
          lrun[mt] += (p0 + p1) + (p2 + p3);
          unsigned plo, phi;
          asm("v_cvt_pk_bf16_f32 %0, %1, %2" : "=v"(plo) : "v"(p0), "v"(p1));
          asm("v_cvt_pk_bf16_f32 %0, %1, %2" : "=v"(phi) : "v"(p2), "v"(p3));
          unsigned long long pk = ((unsigned long long)phi << 32) | plo;
          *(unsigned long long*)&pbase[(mt * 16 + r) * 40 + ntl * 16 + g * 4] = pk;
        }
      }

      // P A-frag read + PV (V loaded just-in-time, 4 regs at a time)
      bf16x8 pf[2];
      #pragma unroll
      for (int mt = 0; mt < 2; mt++)
        pf[mt] = *(const bf16x8*)&pbase[(mt * 16 + r) * 40 + g * 8];
      #pragma unroll
      for (int dt = 0; dt < 4; dt++){
        bf16x8 vf = *(const bf16x8*)&vbase[(size_t)(dt * 16 + r) * NTOK + key0 + g * 8];
        #pragma unroll
        for (int mt = 0; mt < 2; mt++)
          Oa[mt][dt] = __builtin_amdgcn_mfma_f32_16x16x32_bf16(pf[mt], vf, Oa[mt][dt], 0, 0, 0);
      }
    }
  }

  // per-wave row-sums: reduce lrun over g (q = mt*16 + r per lane)
  #pragma unroll
  for (int mt = 0; mt < 2; mt++){
    float l = lrun[mt];
    l += __shfl_xor(l, 16);
    l += __shfl_xor(l, 32);
    if (g == 0) lsh[wv * 32 + mt * 16 + r] = l;
  }
  __syncthreads();   // all waves done with rel_s/P_lds; lsh populated

  #pragma unroll
  for (int mt = 0; mt < 2; mt++)
    #pragma unroll
    for (int reg = 0; reg < 4; reg++){
      int row = mt * 16 + g * 4 + reg;
      #pragma unroll
      for (int dt = 0; dt < 4; dt++)
        Obuf[(wv * 32 + row) * 64 + dt * 16 + r] = Oa[mt][dt][reg];
    }
  __syncthreads();
  {
    int row = tid >> 3;
    int dbase = (tid & 7) * 8;
    float sum[8];
    #pragma unroll
    for (int j = 0; j < 8; j++) sum[j] = 0.f;
    #pragma unroll
    for (int w4 = 0; w4 < 4; w4++){
      const float4* p = (const float4*)&Obuf[(w4 * 32 + row) * 64 + dbase];
      float4 a = p[0], b = p[1];
      sum[0] += a.x; sum[1] += a.y; sum[2] += a.z; sum[3] += a.w;
      sum[4] += b.x; sum[5] += b.y; sum[6] += b.z; sum[7] += b.w;
    }
    float L = lsh[row] + lsh[32 + row] + lsh[64 + row] + lsh[96 + row];
    float invL = 1.f / L;
    union { unsigned short u[8]; bf16x8 v; } o;
    #pragma unroll
    for (int j = 0; j < 8; j++) o.u[j] = f2bf(sum[j] * invL);
    int token = q0 + row;
    *(bf16x8*)&ao[(size_t)token * 768 + head * 64 + dbase] = o.v;
  }
}

// ---------------- proj GEMM ----------------
__global__ __launch_bounds__(256) void proj_gemm(
    const unsigned short* __restrict__ ag,   // [2304][768] bf16
    const unsigned short* __restrict__ wg,   // [768][768] bf16
    const float* __restrict__ bias,
    float* __restrict__ out)
{
  __shared__ short As[128*64];
  __shared__ short Bs[128*64];
  const int tid = threadIdx.x;
  const int lane = tid & 63;
  const int wv = tid >> 6;
  const int r = lane & 15, g = lane >> 4;
  const int wm = (wv >> 1) * 64, wn = (wv & 1) * 64;
  const int m0 = blockIdx.y * 128, n0 = blockIdx.x * 128;

  f32x4 acc[4][4];
  #pragma unroll
  for (int i = 0; i < 4; i++)
    #pragma unroll
    for (int j = 0; j < 4; j++) acc[i][j] = (f32x4){0.f, 0.f, 0.f, 0.f};

  for (int k0 = 0; k0 < 768; k0 += 64){
    __syncthreads();
    #pragma unroll
    for (int it = 0; it < 4; it++){
      int f = it * 256 + tid;
      int row = f >> 3, u = f & 7;
      int us = ((u ^ (row & 7)) << 3);
      gload_lds16(ag + (size_t)(m0 + row) * 768 + k0 + us, &As[f * 8]);
      gload_lds16(wg + (size_t)(n0 + row) * 768 + k0 + us, &Bs[f * 8]);
    }
    __syncthreads();
    #pragma unroll
    for (int ks = 0; ks < 2; ks++){
      bf16x8 af[4], bfr[4];
      #pragma unroll
      for (int mt = 0; mt < 4; mt++){
        int row = wm + mt * 16 + r;
        af[mt] = *(const bf16x8*)&As[row * 64 + ((((ks << 2) | g) ^ (r & 7)) << 3)];
      }
      #pragma unroll
      for (int nt = 0; nt < 4; nt++){
        int row = wn + nt * 16 + r;
        bfr[nt] = *(const bf16x8*)&Bs[row * 64 + ((((ks << 2) | g) ^ (r & 7)) << 3)];
      }
      #pragma unroll
      for (int mt = 0; mt < 4; mt++)
        #pragma unroll
        for (int nt = 0; nt < 4; nt++)
          acc[mt][nt] = __builtin_amdgcn_mfma_f32_16x16x32_bf16(af[mt], bfr[nt], acc[mt][nt], 0, 0, 0);
    }
  }

  #pragma unroll
  for (int mt = 0; mt < 4; mt++)
    #pragma unroll
    for (int reg = 0; reg < 4; reg++){
      int row_m = m0 + wm + mt * 16 + g * 4 + reg;
      #pragma unroll
      for (int nt = 0; nt < 4; nt++){
        int col = n0 + wn + nt * 16 + r;
        out[(size_t)row_m * 768 + col] = acc[mt][nt][reg] + bias[col];
      }
    }
}

extern "C" void kernel_launch(void* const* d_in, const int* in_sizes, int n_in,
                              void* d_out, int out_size, void* d_ws, size_t ws_size,
                              hipStream_t stream){
  (void)in_sizes; (void)n_in; (void)out_size; (void)ws_size;
  const float* x      = (const float*)d_in[0];
  const float* qkv_w  = (const float*)d_in[1];
  const float* qkv_b  = (const float*)d_in[2];
  const float* proj_w = (const float*)d_in[3];
  const float* proj_b = (const float*)d_in[4];
  const float* rph    = (const float*)d_in[5];
  const float* rpw    = (const float*)d_in[6];
  const float* Aq     = (const float*)d_in[7];
  const float* Bq     = (const float*)d_in[8];
  const float* Ak     = (const float*)d_in[9];
  const float* Bk     = (const float*)d_in[10];
  const float* Av     = (const float*)d_in[11];
  const float* Bv     = (const float*)d_in[12];

  char* w = (char*)d_ws;
  unsigned short* xb  = (unsigned short*)(w + 0);         // 2304*768 bf16 (dead after qkv_gemm)
  unsigned short* wqb = (unsigned short*)(w + 3538944);   // 2304*768 bf16
  unsigned short* wpb = (unsigned short*)(w + 7077888);   //  768*768 bf16
  unsigned short* qb  = (unsigned short*)(w + 8257536);   // 12*2304*64 bf16 (scaled)
  unsigned short* kb  = (unsigned short*)(w + 11796480);  // 12*2304*64 bf16
  unsigned short* vtb = (unsigned short*)(w + 15335424);  // 12*64*2304 bf16
  float* tb           = (float*)(w + 18874368);           // 3*2304*4 f32
  float* rhb          = (float*)(w + 18984960);           // 12*2304*48 f32
  float* rwb          = (float*)(w + 24293376);           // 12*2304*48 f32
  unsigned short* aob = (unsigned short*)(w + 29601792);  // 2304*768 bf16
  unsigned short* rphb = (unsigned short*)(w + 0);        // 95*64 bf16 (xb region)
  unsigned short* rpwb = (unsigned short*)(w + 12160);    // 95*64 bf16

  cvt_f32_bf16<<<1728, 256, 0, stream>>>(x, xb, 442368);
  cvt_f32_bf16<<<1728, 256, 0, stream>>>(qkv_w, wqb, 442368);
  cvt_f32_bf16<<<576, 256, 0, stream>>>(proj_w, wpb, 147456);
  lora_t_kernel<<<576, 256, 0, stream>>>(x, Aq, Ak, Av, tb);
  qkv_gemm<<<dim3(18, 18), 256, 0, stream>>>(xb, wqb, qkv_b, tb, Bq, Bk, Bv, qb, kb, vtb);
  cvt_f32_bf16<<<6, 256, 0, stream>>>(rph, rphb, 1520);
  cvt_f32_bf16<<<6, 256, 0, stream>>>(rpw, rpwb, 1520);
  rel_gemm<<<dim3(48, 12), 256, 0, stream>>>(qb, rphb, rpwb, rhb, rwb);
  attn_kernel<<<dim3(72, 12), 256, 0, stream>>>(qb, kb, vtb, rhb, rwb, aob);
  proj_gemm<<<dim3(6, 18), 256, 0, stream>>>(aob, wpb, proj_b, (float*)d_out);
}

// Round 8
// 139.479 us; speedup vs baseline: 3.1082x; 1.1779x over previous
//
#include <hip/hip_runtime.h>

#define NTOK 2304   // 48*48 tokens
#define NH 12
#define HD 64

typedef __attribute__((ext_vector_type(8))) short bf16x8;
typedef __attribute__((ext_vector_type(4))) float f32x4;

__device__ __forceinline__ unsigned short f2bf(float f){
  union { float f; unsigned u; } v; v.f = f;
  unsigned r = v.u + 0x7fffu + ((v.u >> 16) & 1u);
  return (unsigned short)(r >> 16);
}
__device__ __forceinline__ float bf2f(unsigned short h){
  union { unsigned u; float f; } v; v.u = ((unsigned)h) << 16;
  return v.f;
}
__device__ __forceinline__ void gload_lds16(const void* g, void* lds){
  __builtin_amdgcn_global_load_lds(
    (const __attribute__((address_space(1))) unsigned int*)g,
    (__attribute__((address_space(3))) unsigned int*)lds, 16, 0, 0);
}

// ---------------- fp32 -> bf16 convert ----------------
__global__ __launch_bounds__(256) void cvt_f32_bf16(const float* __restrict__ src,
                                                    unsigned short* __restrict__ dst, int n4){
  int i = blockIdx.x * 256 + threadIdx.x;
  if (i >= n4) return;
  float4 v = ((const float4*)src)[i];
  union { unsigned short u[4]; unsigned long long ll; } o;
  o.u[0] = f2bf(v.x); o.u[1] = f2bf(v.y); o.u[2] = f2bf(v.z); o.u[3] = f2bf(v.w);
  ((unsigned long long*)dst)[i] = o.ll;
}

// ---------------- LoRA t = x @ A^T  (t[3][2304][4]) ----------------
__global__ __launch_bounds__(256) void lora_t_kernel(const float* __restrict__ x,
    const float* __restrict__ Aq, const float* __restrict__ Ak, const float* __restrict__ Av,
    float* __restrict__ t){
  int wave = (blockIdx.x * 256 + threadIdx.x) >> 6;   // token
  int lane = threadIdx.x & 63;
  if (wave >= NTOK) return;
  const float* xr = x + (size_t)wave * 768;
  float part[12];
  #pragma unroll
  for (int j = 0; j < 12; j++) part[j] = 0.f;
  for (int k = lane; k < 768; k += 64){
    float xv = xr[k];
    #pragma unroll
    for (int r = 0; r < 4; r++){
      part[r]     += xv * Aq[r*768 + k];
      part[4 + r] += xv * Ak[r*768 + k];
      part[8 + r] += xv * Av[r*768 + k];
    }
  }
  #pragma unroll
  for (int j = 0; j < 12; j++){
    float v = part[j];
    #pragma unroll
    for (int off = 32; off; off >>= 1) v += __shfl_xor(v, off);
    if (lane == 0){
      int mat = j >> 2, r = j & 3;
      t[((size_t)mat * NTOK + wave) * 4 + r] = v;
    }
  }
}

// ---------------- fused qkv GEMM (+bias +LoRA, writes q(scaled),k,vT) ----------------
__global__ __launch_bounds__(256) void qkv_gemm(
    const unsigned short* __restrict__ xg,   // [2304][768] bf16
    const unsigned short* __restrict__ wg,   // [2304][768] bf16
    const float* __restrict__ bias,          // [2304]
    const float* __restrict__ t,             // [3][2304][4]
    const float* __restrict__ Bq, const float* __restrict__ Bk, const float* __restrict__ Bv, // [768][4]
    unsigned short* __restrict__ qo,         // [12][2304][64]  (pre-scaled by 0.125)
    unsigned short* __restrict__ ko,         // [12][2304][64]
    unsigned short* __restrict__ vT)         // [12][64][2304]
{
  __shared__ short As[128*64];
  __shared__ short Bs[128*64];
  const int tid = threadIdx.x;
  const int lane = tid & 63;
  const int wv = tid >> 6;
  const int r = lane & 15, g = lane >> 4;
  const int wm = (wv >> 1) * 64, wn = (wv & 1) * 64;
  const int m0 = blockIdx.y * 128, n0 = blockIdx.x * 128;

  f32x4 acc[4][4];
  #pragma unroll
  for (int i = 0; i < 4; i++)
    #pragma unroll
    for (int j = 0; j < 4; j++) acc[i][j] = (f32x4){0.f, 0.f, 0.f, 0.f};

  for (int k0 = 0; k0 < 768; k0 += 64){
    __syncthreads();
    #pragma unroll
    for (int it = 0; it < 4; it++){
      int f = it * 256 + tid;
      int row = f >> 3, u = f & 7;
      int us = ((u ^ (row & 7)) << 3);
      gload_lds16(xg + (size_t)(m0 + row) * 768 + k0 + us, &As[f * 8]);
      gload_lds16(wg + (size_t)(n0 + row) * 768 + k0 + us, &Bs[f * 8]);
    }
    __syncthreads();
    #pragma unroll
    for (int ks = 0; ks < 2; ks++){
      bf16x8 af[4], bfr[4];
      #pragma unroll
      for (int mt = 0; mt < 4; mt++){
        int row = wm + mt * 16 + r;
        af[mt] = *(const bf16x8*)&As[row * 64 + ((((ks << 2) | g) ^ (r & 7)) << 3)];
      }
      #pragma unroll
      for (int nt = 0; nt < 4; nt++){
        int row = wn + nt * 16 + r;
        bfr[nt] = *(const bf16x8*)&Bs[row * 64 + ((((ks << 2) | g) ^ (r & 7)) << 3)];
      }
      #pragma unroll
      for (int mt = 0; mt < 4; mt++)
        #pragma unroll
        for (int nt = 0; nt < 4; nt++)
          acc[mt][nt] = __builtin_amdgcn_mfma_f32_16x16x32_bf16(af[mt], bfr[nt], acc[mt][nt], 0, 0, 0);
    }
  }

  const int part = n0 / 768;
  const float* Bl = (part == 0) ? Bq : ((part == 1) ? Bk : Bv);
  const float* tp = t + (size_t)part * NTOK * 4;
  #pragma unroll
  for (int mt = 0; mt < 4; mt++){
    #pragma unroll
    for (int reg = 0; reg < 4; reg++){
      int row_m = m0 + wm + mt * 16 + g * 4 + reg;
      float4 tv = *(const float4*)&tp[row_m * 4];
      #pragma unroll
      for (int nt = 0; nt < 4; nt++){
        int col = n0 + wn + nt * 16 + r;
        int cc = col - part * 768;
        float4 bw = *(const float4*)&Bl[cc * 4];
        float val = acc[mt][nt][reg] + bias[col]
                  + 0.25f * (tv.x * bw.x + tv.y * bw.y + tv.z * bw.z + tv.w * bw.w);
        int head = cc >> 6, d = cc & 63;
        if (part == 0)      qo[((size_t)head * NTOK + row_m) * 64 + d] = f2bf(val * 0.125f);
        else if (part == 1) ko[((size_t)head * NTOK + row_m) * 64 + d] = f2bf(val);
        else                vT[((size_t)head * 64 + d) * NTOK + row_m] = f2bf(val);
      }
    }
  }
}

// ---------------- rel_h / rel_w via MFMA ----------------
__global__ __launch_bounds__(256, 2) void rel_gemm(
    const unsigned short* __restrict__ qg,    // [12][2304][64] bf16 (scaled by 0.125)
    const unsigned short* __restrict__ rphb,  // [95][64] bf16
    const unsigned short* __restrict__ rpwb,  // [95][64] bf16
    float* __restrict__ rel_h,                // [12][2304][48]
    float* __restrict__ rel_w)                // [12][2304][48]
{
  __shared__ float G[48 * 196];
  const int ih = blockIdx.x, head = blockIdx.y;
  const int tid = threadIdx.x, lane = tid & 63, wv = tid >> 6;
  const int r = lane & 15, g = lane >> 4;
  const int q0 = ih * 48;

  bf16x8 af[3][2];
  #pragma unroll
  for (int mt = 0; mt < 3; mt++)
    #pragma unroll
    for (int ks = 0; ks < 2; ks++)
      af[mt][ks] = *(const bf16x8*)&qg[((size_t)head * NTOK + q0 + mt * 16 + r) * 64 + ks * 32 + g * 8];

  bf16x8 bf[3][2];
  #pragma unroll
  for (int nt = 0; nt < 3; nt++){
    int col = wv * 48 + nt * 16 + r;
    const unsigned short* src = (col < 95) ? &rphb[(size_t)col * 64]
                              : (col < 190) ? &rpwb[(size_t)(col - 95) * 64]
                              : &rpwb[0];
    #pragma unroll
    for (int ks = 0; ks < 2; ks++)
      bf[nt][ks] = *(const bf16x8*)&src[ks * 32 + g * 8];
  }

  f32x4 acc[3][3];
  #pragma unroll
  for (int mt = 0; mt < 3; mt++)
    #pragma unroll
    for (int nt = 0; nt < 3; nt++) acc[mt][nt] = (f32x4){0.f, 0.f, 0.f, 0.f};
  #pragma unroll
  for (int ks = 0; ks < 2; ks++)
    #pragma unroll
    for (int mt = 0; mt < 3; mt++)
      #pragma unroll
      for (int nt = 0; nt < 3; nt++)
        acc[mt][nt] = __builtin_amdgcn_mfma_f32_16x16x32_bf16(af[mt][ks], bf[nt][ks], acc[mt][nt], 0, 0, 0);

  #pragma unroll
  for (int mt = 0; mt < 3; mt++)
    #pragma unroll
    for (int reg = 0; reg < 4; reg++){
      int row = mt * 16 + g * 4 + reg;
      #pragma unroll
      for (int nt = 0; nt < 3; nt++)
        G[row * 196 + wv * 48 + nt * 16 + r] = acc[mt][nt][reg];
    }
  __syncthreads();

  for (int idx = tid; idx < 48 * 96; idx += 256){
    int i = idx / 96, c = idx % 96;
    size_t gi = (size_t)head * NTOK + q0 + i;
    if (c < 48) rel_h[gi * 48 + c]        = G[i * 196 + (ih + 47 - c)] * 8.f;
    else        rel_w[gi * 48 + (c - 48)] = G[i * 196 + 95 + (i + 47 - (c - 48))] * 8.f;
  }
}

// ---------------- flash attention v7: LDS-staged K/V, double-buffered ----------------
// Block = 64 q-rows, 4 waves (16 q-rows each), full KV sweep per wave (36 tiles of 64).
// K/V tiles staged cooperatively via global_load_lds (pre-swizzled source, XOR on read).
// Per iter: STAGE(t+1, buf^1) -> compute(t, buf) -> barrier.  1 barrier/iter.
// Swapped QK^T, no-max softmax. key = 64t + 16ntl + g*4+reg -> kh = floor(e/3),
// e = 4t+ntl (lane-uniform, no straddle since sublane span 16 <= 48-16*2).
__global__ __launch_bounds__(256, 2) void attn_kernel(
    const unsigned short* __restrict__ qg,   // [12][2304][64] scaled
    const unsigned short* __restrict__ kg,   // [12][2304][64]
    const unsigned short* __restrict__ vT,   // [12][64][2304]
    const float* __restrict__ rel_h,         // [12][2304][48]
    const float* __restrict__ rel_w,         // [12][2304][48]
    unsigned short* __restrict__ ao)         // [2304][768]
{
  // LDS map (bytes): Ks[2][64][64]us @0 (16384) | Vs[2][64][64]us @16384 (16384)
  //                  rel_s[64][100]f32 @32768 (25600) | P_lds[4][16][72]us @58368 (9216)
  //                  lsh[4][16]f32 @67584 (256)   total 67840
  __shared__ __align__(16) char smem[67840];
  unsigned short* Ks = (unsigned short*)smem;
  unsigned short* Vs = (unsigned short*)(smem + 16384);
  float* rel_s = (float*)(smem + 32768);
  unsigned short* P_lds = (unsigned short*)(smem + 58368);
  float* lsh = (float*)(smem + 67584);

  const int head = blockIdx.y;
  const int q0 = blockIdx.x * 64;
  const int tid = threadIdx.x, lane = tid & 63, wv = tid >> 6;
  const int r = lane & 15, g = lane >> 4;

  const unsigned short* kbase = kg + (size_t)head * NTOK * 64;
  const unsigned short* vbase = vT + (size_t)head * 64 * NTOK;

  // rel_s stage: 64 rows x 96
  for (int idx = tid; idx < 64 * 96; idx += 256){
    int i = idx / 96, c = idx % 96;
    int token = head * NTOK + q0 + i;
    rel_s[i * 100 + c] = (c < 48) ? rel_h[(size_t)token * 48 + c]
                                  : rel_w[(size_t)token * 48 + (c - 48)];
  }

  // q fragments (B-operand for swapped QK): 16 q-rows per wave
  bf16x8 qf[2];
  #pragma unroll
  for (int ks = 0; ks < 2; ks++)
    qf[ks] = *(const bf16x8*)&qg[((size_t)head * NTOK + q0 + wv * 16 + r) * 64 + ks * 32 + g * 8];

  // stage helper coords: lane -> (rowIn, unit); per wave 2 segments of 8 rows for K and V
  const int rowIn = lane >> 3, uu = lane & 7;

  // prologue: stage tile 0 into buf 0
  {
    const int key0 = 0;
    #pragma unroll
    for (int s2 = 0; s2 < 2; s2++){
      int seg = wv * 2 + s2;
      int row = seg * 8 + rowIn;
      gload_lds16(kbase + (size_t)(key0 + row) * 64 + ((uu ^ (row & 7)) << 3),
                  &Ks[seg * 512 + lane * 8]);
      gload_lds16(vbase + (size_t)row * NTOK + key0 + ((uu ^ (row & 7)) << 3),
                  &Vs[seg * 512 + lane * 8]);
    }
  }
  __syncthreads();

  f32x4 Oa[4];
  float lrun = 0.f;
  #pragma unroll
  for (int dt = 0; dt < 4; dt++) Oa[dt] = (f32x4){0.f, 0.f, 0.f, 0.f};

  unsigned short* pbase = &P_lds[wv * 16 * 72];
  const float* rs = &rel_s[(wv * 16 + r) * 100];

  // static tables: e = 4t+ntl, t = 3a+tb -> kh = 4a + KH[tb][ntl], j = J[tb][ntl]
  const int KH_T[3][4] = {{0,0,0,1},{1,1,2,2},{2,3,3,3}};
  const int J_T[3][4]  = {{0,1,2,0},{1,2,0,1},{2,0,1,2}};

  int buf = 0;
  for (int a = 0; a < 12; a++){
    #pragma unroll
    for (int tb = 0; tb < 3; tb++){
      const int t = a * 3 + tb;
      unsigned short* KsB = &Ks[buf * 4096];
      unsigned short* VsB = &Vs[buf * 4096];

      // stage tile t+1 into buf^1 (in flight during compute)
      if (t < 35){
        const int key0n = (t + 1) * 64;
        unsigned short* KsN = &Ks[(buf ^ 1) * 4096];
        unsigned short* VsN = &Vs[(buf ^ 1) * 4096];
        #pragma unroll
        for (int s2 = 0; s2 < 2; s2++){
          int seg = wv * 2 + s2;
          int row = seg * 8 + rowIn;
          gload_lds16(kbase + (size_t)(key0n + row) * 64 + ((uu ^ (row & 7)) << 3),
                      &KsN[seg * 512 + lane * 8]);
          gload_lds16(vbase + (size_t)row * NTOK + key0n + ((uu ^ (row & 7)) << 3),
                      &VsN[seg * 512 + lane * 8]);
        }
      }

      // ---- QK^T (swapped): s[ntl] over 64 keys x 16 q ----
      f32x4 s[4];
      #pragma unroll
      for (int ntl = 0; ntl < 4; ntl++){
        bf16x8 kc0 = *(const bf16x8*)&KsB[(ntl * 16 + r) * 64 + ((g ^ (r & 7)) << 3)];
        bf16x8 kc1 = *(const bf16x8*)&KsB[(ntl * 16 + r) * 64 + (((4 + g) ^ (r & 7)) << 3)];
        s[ntl] = (f32x4){0.f, 0.f, 0.f, 0.f};
        s[ntl] = __builtin_amdgcn_mfma_f32_16x16x32_bf16(kc0, qf[0], s[ntl], 0, 0, 0);
        s[ntl] = __builtin_amdgcn_mfma_f32_16x16x32_bf16(kc1, qf[1], s[ntl], 0, 0, 0);
      }

      // ---- bias + exp + pack -> P_lds ----
      #pragma unroll
      for (int ntl = 0; ntl < 4; ntl++){
        float bh = rs[4 * a + KH_T[tb][ntl]];
        float4 w = *(const float4*)&rs[48 + J_T[tb][ntl] * 16 + g * 4];
        float p0 = __expf(s[ntl][0] + bh + w.x);
        float p1 = __expf(s[ntl][1] + bh + w.y);
        float p2 = __expf(s[ntl][2] + bh + w.z);
        float p3 = __expf(s[ntl][3] + bh + w.w);
        lrun += (p0 + p1) + (p2 + p3);
        unsigned plo, phi;
        asm("v_cvt_pk_bf16_f32 %0, %1, %2" : "=v"(plo) : "v"(p0), "v"(p1));
        asm("v_cvt_pk_bf16_f32 %0, %1, %2" : "=v"(phi) : "v"(p2), "v"(p3));
        unsigned long long pk = ((unsigned long long)phi << 32) | plo;
        *(unsigned long long*)&pbase[r * 72 + ntl * 16 + g * 4] = pk;
      }

      // ---- PV: pf (A) x Vs-frag (B) ----
      bf16x8 pf[2];
      #pragma unroll
      for (int ks = 0; ks < 2; ks++)
        pf[ks] = *(const bf16x8*)&pbase[r * 72 + ks * 32 + g * 8];
      #pragma unroll
      for (int dt = 0; dt < 4; dt++){
        #pragma unroll
        for (int ks = 0; ks < 2; ks++){
          bf16x8 vf = *(const bf16x8*)&VsB[(dt * 16 + r) * 64 + (((ks * 4 + g) ^ (r & 7)) << 3)];
          Oa[dt] = __builtin_amdgcn_mfma_f32_16x16x32_bf16(pf[ks], vf, Oa[dt], 0, 0, 0);
        }
      }

      __syncthreads();   // drains stage loads (vmcnt0) + protects buf swap
      buf ^= 1;
    }
  }

  // ---- epilogue: row-sum exchange + normalize + store ----
  {
    float l = lrun;
    l += __shfl_xor(l, 16);
    l += __shfl_xor(l, 32);
    if (lane < 16) lsh[wv * 16 + lane] = l;   // q-row r (g==0 lanes)
  }
  __syncthreads();
  float invL[4];
  #pragma unroll
  for (int reg = 0; reg < 4; reg++) invL[reg] = 1.f / lsh[wv * 16 + g * 4 + reg];
  #pragma unroll
  for (int dt = 0; dt < 4; dt++)
    #pragma unroll
    for (int reg = 0; reg < 4; reg++){
      int token = q0 + wv * 16 + g * 4 + reg;
      ao[(size_t)token * 768 + head * 64 + dt * 16 + r] = f2bf(Oa[dt][reg] * invL[reg]);
    }
}

// ---------------- proj GEMM ----------------
__global__ __launch_bounds__(256) void proj_gemm(
    const unsigned short* __restrict__ ag,   // [2304][768] bf16
    const unsigned short* __restrict__ wg,   // [768][768] bf16
    const float* __restrict__ bias,
    float* __restrict__ out)
{
  __shared__ short As[128*64];
  __shared__ short Bs[128*64];
  const int tid = threadIdx.x;
  const int lane = tid & 63;
  const int wv = tid >> 6;
  const int r = lane & 15, g = lane >> 4;
  const int wm = (wv >> 1) * 64, wn = (wv & 1) * 64;
  const int m0 = blockIdx.y * 128, n0 = blockIdx.x * 128;

  f32x4 acc[4][4];
  #pragma unroll
  for (int i = 0; i < 4; i++)
    #pragma unroll
    for (int j = 0; j < 4; j++) acc[i][j] = (f32x4){0.f, 0.f, 0.f, 0.f};

  for (int k0 = 0; k0 < 768; k0 += 64){
    __syncthreads();
    #pragma unroll
    for (int it = 0; it < 4; it++){
      int f = it * 256 + tid;
      int row = f >> 3, u = f & 7;
      int us = ((u ^ (row & 7)) << 3);
      gload_lds16(ag + (size_t)(m0 + row) * 768 + k0 + us, &As[f * 8]);
      gload_lds16(wg + (size_t)(n0 + row) * 768 + k0 + us, &Bs[f * 8]);
    }
    __syncthreads();
    #pragma unroll
    for (int ks = 0; ks < 2; ks++){
      bf16x8 af[4], bfr[4];
      #pragma unroll
      for (int mt = 0; mt < 4; mt++){
        int row = wm + mt * 16 + r;
        af[mt] = *(const bf16x8*)&As[row * 64 + ((((ks << 2) | g) ^ (r & 7)) << 3)];
      }
      #pragma unroll
      for (int nt = 0; nt < 4; nt++){
        int row = wn + nt * 16 + r;
        bfr[nt] = *(const bf16x8*)&Bs[row * 64 + ((((ks << 2) | g) ^ (r & 7)) << 3)];
      }
      #pragma unroll
      for (int mt = 0; mt < 4; mt++)
        #pragma unroll
        for (int nt = 0; nt < 4; nt++)
          acc[mt][nt] = __builtin_amdgcn_mfma_f32_16x16x32_bf16(af[mt], bfr[nt], acc[mt][nt], 0, 0, 0);
    }
  }

  #pragma unroll
  for (int mt = 0; mt < 4; mt++)
    #pragma unroll
    for (int reg = 0; reg < 4; reg++){
      int row_m = m0 + wm + mt * 16 + g * 4 + reg;
      #pragma unroll
      for (int nt = 0; nt < 4; nt++){
        int col = n0 + wn + nt * 16 + r;
        out[(size_t)row_m * 768 + col] = acc[mt][nt][reg] + bias[col];
      }
    }
}

extern "C" void kernel_launch(void* const* d_in, const int* in_sizes, int n_in,
                              void* d_out, int out_size, void* d_ws, size_t ws_size,
                              hipStream_t stream){
  (void)in_sizes; (void)n_in; (void)out_size; (void)ws_size;
  const float* x      = (const float*)d_in[0];
  const float* qkv_w  = (const float*)d_in[1];
  const float* qkv_b  = (const float*)d_in[2];
  const float* proj_w = (const float*)d_in[3];
  const float* proj_b = (const float*)d_in[4];
  const float* rph    = (const float*)d_in[5];
  const float* rpw    = (const float*)d_in[6];
  const float* Aq     = (const float*)d_in[7];
  const float* Bq     = (const float*)d_in[8];
  const float* Ak     = (const float*)d_in[9];
  const float* Bk     = (const float*)d_in[10];
  const float* Av     = (const float*)d_in[11];
  const float* Bv     = (const float*)d_in[12];

  char* w = (char*)d_ws;
  unsigned short* xb  = (unsigned short*)(w + 0);         // 2304*768 bf16 (dead after qkv_gemm)
  unsigned short* wqb = (unsigned short*)(w + 3538944);   // 2304*768 bf16
  unsigned short* wpb = (unsigned short*)(w + 7077888);   //  768*768 bf16
  unsigned short* qb  = (unsigned short*)(w + 8257536);   // 12*2304*64 bf16 (scaled)
  unsigned short* kb  = (unsigned short*)(w + 11796480);  // 12*2304*64 bf16
  unsigned short* vtb = (unsigned short*)(w + 15335424);  // 12*64*2304 bf16
  float* tb           = (float*)(w + 18874368);           // 3*2304*4 f32
  float* rhb          = (float*)(w + 18984960);           // 12*2304*48 f32
  float* rwb          = (float*)(w + 24293376);           // 12*2304*48 f32
  unsigned short* aob = (unsigned short*)(w + 29601792);  // 2304*768 bf16
  unsigned short* rphb = (unsigned short*)(w + 0);        // 95*64 bf16 (xb region)
  unsigned short* rpwb = (unsigned short*)(w + 12160);    // 95*64 bf16

  cvt_f32_bf16<<<1728, 256, 0, stream>>>(x, xb, 442368);
  cvt_f32_bf16<<<1728, 256, 0, stream>>>(qkv_w, wqb, 442368);
  cvt_f32_bf16<<<576, 256, 0, stream>>>(proj_w, wpb, 147456);
  lora_t_kernel<<<576, 256, 0, stream>>>(x, Aq, Ak, Av, tb);
  qkv_gemm<<<dim3(18, 18), 256, 0, stream>>>(xb, wqb, qkv_b, tb, Bq, Bk, Bv, qb, kb, vtb);
  cvt_f32_bf16<<<6, 256, 0, stream>>>(rph, rphb, 1520);
  cvt_f32_bf16<<<6, 256, 0, stream>>>(rpw, rpwb, 1520);
  rel_gemm<<<dim3(48, 12), 256, 0, stream>>>(qb, rphb, rpwb, rhb, rwb);
  attn_kernel<<<dim3(36, 12), 256, 0, stream>>>(qb, kb, vtb, rhb, rwb, aob);
  proj_gemm<<<dim3(6, 18), 256, 0, stream>>>(aob, wpb, proj_b, (float*)d_out);
}

// Round 10
// 126.348 us; speedup vs baseline: 3.4312x; 1.1039x over previous
//
#include <hip/hip_runtime.h>

#define NTOK 2304   // 48*48 tokens
#define NH 12
#define HD 64

typedef __attribute__((ext_vector_type(8))) short bf16x8;
typedef __attribute__((ext_vector_type(4))) float f32x4;

__device__ __forceinline__ unsigned short f2bf(float f){
  union { float f; unsigned u; } v; v.f = f;
  unsigned r = v.u + 0x7fffu + ((v.u >> 16) & 1u);
  return (unsigned short)(r >> 16);
}
__device__ __forceinline__ float bf2f(unsigned short h){
  union { unsigned u; float f; } v; v.u = ((unsigned)h) << 16;
  return v.f;
}
__device__ __forceinline__ void gload_lds16(const void* g, void* lds){
  __builtin_amdgcn_global_load_lds(
    (const __attribute__((address_space(1))) unsigned int*)g,
    (__attribute__((address_space(3))) unsigned int*)lds, 16, 0, 0);
}

// ---------------- fused fp32 -> bf16 convert (x, qkv_w, proj_w) ----------------
__global__ __launch_bounds__(256) void cvt_all(
    const float* __restrict__ x, const float* __restrict__ qw, const float* __restrict__ pw,
    unsigned short* __restrict__ xb, unsigned short* __restrict__ wqb, unsigned short* __restrict__ wpb){
  int i = blockIdx.x * 256 + threadIdx.x;   // 1032192 float4 units total
  const float* src; unsigned short* dst; int off;
  if (i < 442368)      { src = x;  dst = xb;  off = i; }
  else if (i < 884736) { src = qw; dst = wqb; off = i - 442368; }
  else                 { src = pw; dst = wpb; off = i - 884736; }
  float4 v = ((const float4*)src)[off];
  union { unsigned short u[4]; unsigned long long ll; } o;
  o.u[0] = f2bf(v.x); o.u[1] = f2bf(v.y); o.u[2] = f2bf(v.z); o.u[3] = f2bf(v.w);
  ((unsigned long long*)dst)[off] = o.ll;
}

// ---------------- LoRA t = x @ A^T  (t[3][2304][4]) ----------------
__global__ __launch_bounds__(256) void lora_t_kernel(const float* __restrict__ x,
    const float* __restrict__ Aq, const float* __restrict__ Ak, const float* __restrict__ Av,
    float* __restrict__ t){
  int wave = (blockIdx.x * 256 + threadIdx.x) >> 6;   // token
  int lane = threadIdx.x & 63;
  if (wave >= NTOK) return;
  const float* xr = x + (size_t)wave * 768;
  float part[12];
  #pragma unroll
  for (int j = 0; j < 12; j++) part[j] = 0.f;
  for (int k = lane; k < 768; k += 64){
    float xv = xr[k];
    #pragma unroll
    for (int r = 0; r < 4; r++){
      part[r]     += xv * Aq[r*768 + k];
      part[4 + r] += xv * Ak[r*768 + k];
      part[8 + r] += xv * Av[r*768 + k];
    }
  }
  #pragma unroll
  for (int j = 0; j < 12; j++){
    float v = part[j];
    #pragma unroll
    for (int off = 32; off; off >>= 1) v += __shfl_xor(v, off);
    if (lane == 0){
      int mat = j >> 2, r = j & 3;
      t[((size_t)mat * NTOK + wave) * 4 + r] = v;
    }
  }
}

// ---------------- fused qkv GEMM (+bias +LoRA, writes q(scaled),k,vT) ----------------
__global__ __launch_bounds__(256) void qkv_gemm(
    const unsigned short* __restrict__ xg,   // [2304][768] bf16
    const unsigned short* __restrict__ wg,   // [2304][768] bf16
    const float* __restrict__ bias,          // [2304]
    const float* __restrict__ t,             // [3][2304][4]
    const float* __restrict__ Bq, const float* __restrict__ Bk, const float* __restrict__ Bv, // [768][4]
    unsigned short* __restrict__ qo,         // [12][2304][64]  (pre-scaled by 0.125)
    unsigned short* __restrict__ ko,         // [12][2304][64]
    unsigned short* __restrict__ vT)         // [12][64][2304]
{
  __shared__ short As[128*64];
  __shared__ short Bs[128*64];
  const int tid = threadIdx.x;
  const int lane = tid & 63;
  const int wv = tid >> 6;
  const int r = lane & 15, g = lane >> 4;
  const int wm = (wv >> 1) * 64, wn = (wv & 1) * 64;
  const int m0 = blockIdx.y * 128, n0 = blockIdx.x * 128;

  f32x4 acc[4][4];
  #pragma unroll
  for (int i = 0; i < 4; i++)
    #pragma unroll
    for (int j = 0; j < 4; j++) acc[i][j] = (f32x4){0.f, 0.f, 0.f, 0.f};

  for (int k0 = 0; k0 < 768; k0 += 64){
    __syncthreads();
    #pragma unroll
    for (int it = 0; it < 4; it++){
      int f = it * 256 + tid;
      int row = f >> 3, u = f & 7;
      int us = ((u ^ (row & 7)) << 3);
      gload_lds16(xg + (size_t)(m0 + row) * 768 + k0 + us, &As[f * 8]);
      gload_lds16(wg + (size_t)(n0 + row) * 768 + k0 + us, &Bs[f * 8]);
    }
    __syncthreads();
    #pragma unroll
    for (int ks = 0; ks < 2; ks++){
      bf16x8 af[4], bfr[4];
      #pragma unroll
      for (int mt = 0; mt < 4; mt++){
        int row = wm + mt * 16 + r;
        af[mt] = *(const bf16x8*)&As[row * 64 + ((((ks << 2) | g) ^ (r & 7)) << 3)];
      }
      #pragma unroll
      for (int nt = 0; nt < 4; nt++){
        int row = wn + nt * 16 + r;
        bfr[nt] = *(const bf16x8*)&Bs[row * 64 + ((((ks << 2) | g) ^ (r & 7)) << 3)];
      }
      #pragma unroll
      for (int mt = 0; mt < 4; mt++)
        #pragma unroll
        for (int nt = 0; nt < 4; nt++)
          acc[mt][nt] = __builtin_amdgcn_mfma_f32_16x16x32_bf16(af[mt], bfr[nt], acc[mt][nt], 0, 0, 0);
    }
  }

  const int part = n0 / 768;
  const float* Bl = (part == 0) ? Bq : ((part == 1) ? Bk : Bv);
  const float* tp = t + (size_t)part * NTOK * 4;
  #pragma unroll
  for (int mt = 0; mt < 4; mt++){
    #pragma unroll
    for (int reg = 0; reg < 4; reg++){
      int row_m = m0 + wm + mt * 16 + g * 4 + reg;
      float4 tv = *(const float4*)&tp[row_m * 4];
      #pragma unroll
      for (int nt = 0; nt < 4; nt++){
        int col = n0 + wn + nt * 16 + r;
        int cc = col - part * 768;
        float4 bw = *(const float4*)&Bl[cc * 4];
        float val = acc[mt][nt][reg] + bias[col]
                  + 0.25f * (tv.x * bw.x + tv.y * bw.y + tv.z * bw.z + tv.w * bw.w);
        int head = cc >> 6, d = cc & 63;
        if (part == 0)      qo[((size_t)head * NTOK + row_m) * 64 + d] = f2bf(val * 0.125f);
        else if (part == 1) ko[((size_t)head * NTOK + row_m) * 64 + d] = f2bf(val);
        else                vT[((size_t)head * 64 + d) * NTOK + row_m] = f2bf(val);
      }
    }
  }
}

// ---------------- rel_h / rel_w via MFMA (rel_pos converted in-kernel) ----------------
__global__ __launch_bounds__(256, 2) void rel_gemm(
    const unsigned short* __restrict__ qg,    // [12][2304][64] bf16 (scaled by 0.125)
    const float* __restrict__ rph,            // [95][64] f32
    const float* __restrict__ rpw,            // [95][64] f32
    float* __restrict__ rel_h,                // [12][2304][48]
    float* __restrict__ rel_w)                // [12][2304][48]
{
  __shared__ float G[48 * 196];
  const int ih = blockIdx.x, head = blockIdx.y;
  const int tid = threadIdx.x, lane = tid & 63, wv = tid >> 6;
  const int r = lane & 15, g = lane >> 4;
  const int q0 = ih * 48;

  bf16x8 af[3][2];
  #pragma unroll
  for (int mt = 0; mt < 3; mt++)
    #pragma unroll
    for (int ks = 0; ks < 2; ks++)
      af[mt][ks] = *(const bf16x8*)&qg[((size_t)head * NTOK + q0 + mt * 16 + r) * 64 + ks * 32 + g * 8];

  bf16x8 bfv[3][2];
  #pragma unroll
  for (int nt = 0; nt < 3; nt++){
    int col = wv * 48 + nt * 16 + r;
    const float* src = (col < 95) ? &rph[(size_t)col * 64]
                     : (col < 190) ? &rpw[(size_t)(col - 95) * 64]
                     : &rpw[0];
    #pragma unroll
    for (int ks = 0; ks < 2; ks++){
      float4 lo = *(const float4*)&src[ks * 32 + g * 8];
      float4 hi = *(const float4*)&src[ks * 32 + g * 8 + 4];
      union { unsigned short u[8]; bf16x8 v; } t;
      t.u[0] = f2bf(lo.x); t.u[1] = f2bf(lo.y); t.u[2] = f2bf(lo.z); t.u[3] = f2bf(lo.w);
      t.u[4] = f2bf(hi.x); t.u[5] = f2bf(hi.y); t.u[6] = f2bf(hi.z); t.u[7] = f2bf(hi.w);
      bfv[nt][ks] = t.v;
    }
  }

  f32x4 acc[3][3];
  #pragma unroll
  for (int mt = 0; mt < 3; mt++)
    #pragma unroll
    for (int nt = 0; nt < 3; nt++) acc[mt][nt] = (f32x4){0.f, 0.f, 0.f, 0.f};
  #pragma unroll
  for (int ks = 0; ks < 2; ks++)
    #pragma unroll
    for (int mt = 0; mt < 3; mt++)
      #pragma unroll
      for (int nt = 0; nt < 3; nt++)
        acc[mt][nt] = __builtin_amdgcn_mfma_f32_16x16x32_bf16(af[mt][ks], bfv[nt][ks], acc[mt][nt], 0, 0, 0);

  #pragma unroll
  for (int mt = 0; mt < 3; mt++)
    #pragma unroll
    for (int reg = 0; reg < 4; reg++){
      int row = mt * 16 + g * 4 + reg;
      #pragma unroll
      for (int nt = 0; nt < 3; nt++)
        G[row * 196 + wv * 48 + nt * 16 + r] = acc[mt][nt][reg];
    }
  __syncthreads();

  for (int idx = tid; idx < 48 * 96; idx += 256){
    int i = idx / 96, c = idx % 96;
    size_t gi = (size_t)head * NTOK + q0 + i;
    if (c < 48) rel_h[gi * 48 + c]        = G[i * 196 + (ih + 47 - c)] * 8.f;
    else        rel_w[gi * 48 + (c - 48)] = G[i * 196 + 95 + (i + 47 - (c - 48))] * 8.f;
  }
}

// ---------------- flash attention v9 ----------------
// 64 q-rows/block, 4 waves (16 q each), LDS-staged K/V double-buffered.
// P redistribution in-register (16 shfl + 8 select). rel_h: f32 LDS [64][52];
// rel_w: 3 static float4s per lane in VGPRs (full f32 precision).
// LDS 46336 B -> 3 blocks/CU at (256,3).
__global__ __launch_bounds__(256, 3) void attn_kernel(
    const unsigned short* __restrict__ qg,   // [12][2304][64] scaled
    const unsigned short* __restrict__ kg,   // [12][2304][64]
    const unsigned short* __restrict__ vT,   // [12][64][2304]
    const float* __restrict__ rel_h,         // [12][2304][48]
    const float* __restrict__ rel_w,         // [12][2304][48]
    unsigned short* __restrict__ ao)         // [2304][768]
{
  // Ks[2][64][64]us @0 | Vs[2][64][64]us @16384 | relH[64][52]f32 @32768 | lsh @46080
  __shared__ __align__(16) char smem[46336];
  unsigned short* Ks = (unsigned short*)smem;
  unsigned short* Vs = (unsigned short*)(smem + 16384);
  float* relH = (float*)(smem + 32768);
  float* lsh = (float*)(smem + 46080);

  const int head = blockIdx.y;
  const int q0 = blockIdx.x * 64;
  const int tid = threadIdx.x, lane = tid & 63, wv = tid >> 6;
  const int r = lane & 15, g = lane >> 4;

  const unsigned short* kbase = kg + (size_t)head * NTOK * 64;
  const unsigned short* vbase = vT + (size_t)head * 64 * NTOK;

  // rel_h stage (f32, stride 52 -> 16B-aligned rows, float4)
  for (int idx = tid; idx < 64 * 12; idx += 256){
    int i = idx / 12, c4 = idx % 12;
    *(float4*)&relH[i * 52 + c4 * 4] =
        *(const float4*)&rel_h[((size_t)head * NTOK + q0 + i) * 48 + c4 * 4];
  }

  // rel_w: 3 static float4s per lane (row = wv*16+r, cols 16j+4g..+3), full f32
  float4 wreg[3];
  #pragma unroll
  for (int j = 0; j < 3; j++)
    wreg[j] = *(const float4*)&rel_w[((size_t)head * NTOK + q0 + wv * 16 + r) * 48 + j * 16 + g * 4];

  bf16x8 qf[2];
  #pragma unroll
  for (int ks = 0; ks < 2; ks++)
    qf[ks] = *(const bf16x8*)&qg[((size_t)head * NTOK + q0 + wv * 16 + r) * 64 + ks * 32 + g * 8];

  const int rowIn = lane >> 3, uu = lane & 7;

  // prologue: stage tile 0 into buf 0
  #pragma unroll
  for (int s2 = 0; s2 < 2; s2++){
    int seg = wv * 2 + s2;
    int row = seg * 8 + rowIn;
    gload_lds16(kbase + (size_t)row * 64 + ((uu ^ (row & 7)) << 3), &Ks[seg * 512 + lane * 8]);
    gload_lds16(vbase + (size_t)row * NTOK + ((uu ^ (row & 7)) << 3), &Vs[seg * 512 + lane * 8]);
  }
  __syncthreads();

  f32x4 Oa[4];
  float lrun = 0.f;
  #pragma unroll
  for (int dt = 0; dt < 4; dt++) Oa[dt] = (f32x4){0.f, 0.f, 0.f, 0.f};

  const float* rsh = &relH[(wv * 16 + r) * 52];

  // e = 4t+ntl, t = 3a+tb -> kh = 4a + KH[tb][ntl], j = J[tb][ntl]
  const int KH_T[3][4] = {{0,0,0,1},{1,1,2,2},{2,3,3,3}};
  const int J_T[3][4]  = {{0,1,2,0},{1,2,0,1},{2,0,1,2}};

  const int srcA = r + ((g & 1) << 5);   // lane (r, 2*(g&1))
  const int srcB = srcA + 16;            // lane (r, 2*(g&1)+1)
  const int hi = (g >> 1);

  int buf = 0;
  for (int a = 0; a < 12; a++){
    #pragma unroll
    for (int tb = 0; tb < 3; tb++){
      const int t = a * 3 + tb;
      unsigned short* KsB = &Ks[buf * 4096];
      unsigned short* VsB = &Vs[buf * 4096];

      if (t < 35){
        const int key0n = (t + 1) * 64;
        unsigned short* KsN = &Ks[(buf ^ 1) * 4096];
        unsigned short* VsN = &Vs[(buf ^ 1) * 4096];
        #pragma unroll
        for (int s2 = 0; s2 < 2; s2++){
          int seg = wv * 2 + s2;
          int row = seg * 8 + rowIn;
          gload_lds16(kbase + (size_t)(key0n + row) * 64 + ((uu ^ (row & 7)) << 3),
                      &KsN[seg * 512 + lane * 8]);
          gload_lds16(vbase + (size_t)row * NTOK + key0n + ((uu ^ (row & 7)) << 3),
                      &VsN[seg * 512 + lane * 8]);
        }
      }

      // ---- QK^T (swapped): s[ntl] = S[key=16ntl+4g+reg][q=r] ----
      f32x4 s[4];
      __builtin_amdgcn_s_setprio(1);
      #pragma unroll
      for (int ntl = 0; ntl < 4; ntl++){
        bf16x8 kc0 = *(const bf16x8*)&KsB[(ntl * 16 + r) * 64 + ((g ^ (r & 7)) << 3)];
        bf16x8 kc1 = *(const bf16x8*)&KsB[(ntl * 16 + r) * 64 + (((4 + g) ^ (r & 7)) << 3)];
        s[ntl] = (f32x4){0.f, 0.f, 0.f, 0.f};
        s[ntl] = __builtin_amdgcn_mfma_f32_16x16x32_bf16(kc0, qf[0], s[ntl], 0, 0, 0);
        s[ntl] = __builtin_amdgcn_mfma_f32_16x16x32_bf16(kc1, qf[1], s[ntl], 0, 0, 0);
      }
      __builtin_amdgcn_s_setprio(0);

      // ---- bias + exp + pack (W0/W1 per ntl) ----
      unsigned W0[4], W1[4];
      #pragma unroll
      for (int ntl = 0; ntl < 4; ntl++){
        float bh = rsh[4 * a + KH_T[tb][ntl]];
        float4 w = wreg[J_T[tb][ntl]];
        float p0 = __expf(s[ntl][0] + bh + w.x);
        float p1 = __expf(s[ntl][1] + bh + w.y);
        float p2 = __expf(s[ntl][2] + bh + w.z);
        float p3 = __expf(s[ntl][3] + bh + w.w);
        lrun += (p0 + p1) + (p2 + p3);
        asm("v_cvt_pk_bf16_f32 %0, %1, %2" : "=v"(W0[ntl]) : "v"(p0), "v"(p1));
        asm("v_cvt_pk_bf16_f32 %0, %1, %2" : "=v"(W1[ntl]) : "v"(p2), "v"(p3));
      }

      // ---- in-register P redistribution: pf[ks] elem j = key 32ks+8g+j ----
      bf16x8 pf[2];
      #pragma unroll
      for (int ks = 0; ks < 2; ks++){
        unsigned a0 = (unsigned)__shfl((int)W0[2*ks],   srcA);
        unsigned a1 = (unsigned)__shfl((int)W0[2*ks+1], srcA);
        unsigned b0 = (unsigned)__shfl((int)W1[2*ks],   srcA);
        unsigned b1 = (unsigned)__shfl((int)W1[2*ks+1], srcA);
        unsigned c0 = (unsigned)__shfl((int)W0[2*ks],   srcB);
        unsigned c1 = (unsigned)__shfl((int)W0[2*ks+1], srcB);
        unsigned d0 = (unsigned)__shfl((int)W1[2*ks],   srcB);
        unsigned d1 = (unsigned)__shfl((int)W1[2*ks+1], srcB);
        union { unsigned w[4]; bf16x8 v; } u;
        u.w[0] = hi ? a1 : a0;
        u.w[1] = hi ? b1 : b0;
        u.w[2] = hi ? c1 : c0;
        u.w[3] = hi ? d1 : d0;
        pf[ks] = u.v;
      }

      // ---- PV ----
      __builtin_amdgcn_s_setprio(1);
      #pragma unroll
      for (int dt = 0; dt < 4; dt++){
        #pragma unroll
        for (int ks = 0; ks < 2; ks++){
          bf16x8 vf = *(const bf16x8*)&VsB[(dt * 16 + r) * 64 + (((ks * 4 + g) ^ (r & 7)) << 3)];
          Oa[dt] = __builtin_amdgcn_mfma_f32_16x16x32_bf16(pf[ks], vf, Oa[dt], 0, 0, 0);
        }
      }
      __builtin_amdgcn_s_setprio(0);

      __syncthreads();   // drains stage loads + protects buf swap
      buf ^= 1;
    }
  }

  // ---- epilogue ----
  {
    float l = lrun;
    l += __shfl_xor(l, 16);
    l += __shfl_xor(l, 32);
    if (lane < 16) lsh[wv * 16 + lane] = l;
  }
  __syncthreads();
  float invL[4];
  #pragma unroll
  for (int reg = 0; reg < 4; reg++) invL[reg] = 1.f / lsh[wv * 16 + g * 4 + reg];
  #pragma unroll
  for (int dt = 0; dt < 4; dt++)
    #pragma unroll
    for (int reg = 0; reg < 4; reg++){
      int token = q0 + wv * 16 + g * 4 + reg;
      ao[(size_t)token * 768 + head * 64 + dt * 16 + r] = f2bf(Oa[dt][reg] * invL[reg]);
    }
}

// ---------------- proj GEMM ----------------
__global__ __launch_bounds__(256) void proj_gemm(
    const unsigned short* __restrict__ ag,   // [2304][768] bf16
    const unsigned short* __restrict__ wg,   // [768][768] bf16
    const float* __restrict__ bias,
    float* __restrict__ out)
{
  __shared__ short As[128*64];
  __shared__ short Bs[128*64];
  const int tid = threadIdx.x;
  const int lane = tid & 63;
  const int wv = tid >> 6;
  const int r = lane & 15, g = lane >> 4;
  const int wm = (wv >> 1) * 64, wn = (wv & 1) * 64;
  const int m0 = blockIdx.y * 128, n0 = blockIdx.x * 128;

  f32x4 acc[4][4];
  #pragma unroll
  for (int i = 0; i < 4; i++)
    #pragma unroll
    for (int j = 0; j < 4; j++) acc[i][j] = (f32x4){0.f, 0.f, 0.f, 0.f};

  for (int k0 = 0; k0 < 768; k0 += 64){
    __syncthreads();
    #pragma unroll
    for (int it = 0; it < 4; it++){
      int f = it * 256 + tid;
      int row = f >> 3, u = f & 7;
      int us = ((u ^ (row & 7)) << 3);
      gload_lds16(ag + (size_t)(m0 + row) * 768 + k0 + us, &As[f * 8]);
      gload_lds16(wg + (size_t)(n0 + row) * 768 + k0 + us, &Bs[f * 8]);
    }
    __syncthreads();
    #pragma unroll
    for (int ks = 0; ks < 2; ks++){
      bf16x8 af[4], bfr[4];
      #pragma unroll
      for (int mt = 0; mt < 4; mt++){
        int row = wm + mt * 16 + r;
        af[mt] = *(const bf16x8*)&As[row * 64 + ((((ks << 2) | g) ^ (r & 7)) << 3)];
      }
      #pragma unroll
      for (int nt = 0; nt < 4; nt++){
        int row = wn + nt * 16 + r;
        bfr[nt] = *(const bf16x8*)&Bs[row * 64 + ((((ks << 2) | g) ^ (r & 7)) << 3)];
      }
      #pragma unroll
      for (int mt = 0; mt < 4; mt++)
        #pragma unroll
        for (int nt = 0; nt < 4; nt++)
          acc[mt][nt] = __builtin_amdgcn_mfma_f32_16x16x32_bf16(af[mt], bfr[nt], acc[mt][nt], 0, 0, 0);
    }
  }

  #pragma unroll
  for (int mt = 0; mt < 4; mt++)
    #pragma unroll
    for (int reg = 0; reg < 4; reg++){
      int row_m = m0 + wm + mt * 16 + g * 4 + reg;
      #pragma unroll
      for (int nt = 0; nt < 4; nt++){
        int col = n0 + wn + nt * 16 + r;
        out[(size_t)row_m * 768 + col] = acc[mt][nt][reg] + bias[col];
      }
    }
}

extern "C" void kernel_launch(void* const* d_in, const int* in_sizes, int n_in,
                              void* d_out, int out_size, void* d_ws, size_t ws_size,
                              hipStream_t stream){
  (void)in_sizes; (void)n_in; (void)out_size; (void)ws_size;
  const float* x      = (const float*)d_in[0];
  const float* qkv_w  = (const float*)d_in[1];
  const float* qkv_b  = (const float*)d_in[2];
  const float* proj_w = (const float*)d_in[3];
  const float* proj_b = (const float*)d_in[4];
  const float* rph    = (const float*)d_in[5];
  const float* rpw    = (const float*)d_in[6];
  const float* Aq     = (const float*)d_in[7];
  const float* Bq     = (const float*)d_in[8];
  const float* Ak     = (const float*)d_in[9];
  const float* Bk     = (const float*)d_in[10];
  const float* Av     = (const float*)d_in[11];
  const float* Bv     = (const float*)d_in[12];

  char* w = (char*)d_ws;
  unsigned short* xb  = (unsigned short*)(w + 0);         // 2304*768 bf16
  unsigned short* wqb = (unsigned short*)(w + 3538944);   // 2304*768 bf16
  unsigned short* wpb = (unsigned short*)(w + 7077888);   //  768*768 bf16
  unsigned short* qb  = (unsigned short*)(w + 8257536);   // 12*2304*64 bf16 (scaled)
  unsigned short* kb  = (unsigned short*)(w + 11796480);  // 12*2304*64 bf16
  unsigned short* vtb = (unsigned short*)(w + 15335424);  // 12*64*2304 bf16
  float* tb           = (float*)(w + 18874368);           // 3*2304*4 f32
  float* rhb          = (float*)(w + 18984960);           // 12*2304*48 f32
  float* rwb          = (float*)(w + 24293376);           // 12*2304*48 f32
  unsigned short* aob = (unsigned short*)(w + 29601792);  // 2304*768 bf16

  cvt_all<<<4032, 256, 0, stream>>>(x, qkv_w, proj_w, xb, wqb, wpb);
  lora_t_kernel<<<576, 256, 0, stream>>>(x, Aq, Ak, Av, tb);
  qkv_gemm<<<dim3(18, 18), 256, 0, stream>>>(xb, wqb, qkv_b, tb, Bq, Bk, Bv, qb, kb, vtb);
  rel_gemm<<<dim3(48, 12), 256, 0, stream>>>(qb, rph, rpw, rhb, rwb);
  attn_kernel<<<dim3(36, 12), 256, 0, stream>>>(qb, kb, vtb, rhb, rwb, aob);
  proj_gemm<<<dim3(6, 18), 256, 0, stream>>>(aob, wpb, proj_b, (float*)d_out);
}

// Round 12
// 110.947 us; speedup vs baseline: 3.9075x; 1.1388x over previous
//
#include <hip/hip_runtime.h>

#define NTOK 2304   // 48*48 tokens
#define NH 12
#define HD 64

typedef __attribute__((ext_vector_type(8))) short bf16x8;
typedef __attribute__((ext_vector_type(4))) float f32x4;

__device__ __forceinline__ unsigned short f2bf(float f){
  union { float f; unsigned u; } v; v.f = f;
  unsigned r = v.u + 0x7fffu + ((v.u >> 16) & 1u);
  return (unsigned short)(r >> 16);
}
__device__ __forceinline__ float bf2f(unsigned short h){
  union { unsigned u; float f; } v; v.u = ((unsigned)h) << 16;
  return v.f;
}
__device__ __forceinline__ void gload_lds16(const void* g, void* lds){
  __builtin_amdgcn_global_load_lds(
    (const __attribute__((address_space(1))) unsigned int*)g,
    (__attribute__((address_space(3))) unsigned int*)lds, 16, 0, 0);
}

// ---------------- fused fp32 -> bf16 convert (x, qkv_w, proj_w) ----------------
__global__ __launch_bounds__(256) void cvt_all(
    const float* __restrict__ x, const float* __restrict__ qw, const float* __restrict__ pw,
    unsigned short* __restrict__ xb, unsigned short* __restrict__ wqb, unsigned short* __restrict__ wpb){
  int i = blockIdx.x * 256 + threadIdx.x;   // 1032192 float4 units total
  const float* src; unsigned short* dst; int off;
  if (i < 442368)      { src = x;  dst = xb;  off = i; }
  else if (i < 884736) { src = qw; dst = wqb; off = i - 442368; }
  else                 { src = pw; dst = wpb; off = i - 884736; }
  float4 v = ((const float4*)src)[off];
  union { unsigned short u[4]; unsigned long long ll; } o;
  o.u[0] = f2bf(v.x); o.u[1] = f2bf(v.y); o.u[2] = f2bf(v.z); o.u[3] = f2bf(v.w);
  ((unsigned long long*)dst)[off] = o.ll;
}

// ---------------- LoRA t = x @ A^T  (t[3][2304][4]) ----------------
__global__ __launch_bounds__(256) void lora_t_kernel(const float* __restrict__ x,
    const float* __restrict__ Aq, const float* __restrict__ Ak, const float* __restrict__ Av,
    float* __restrict__ t){
  int wave = (blockIdx.x * 256 + threadIdx.x) >> 6;   // token
  int lane = threadIdx.x & 63;
  if (wave >= NTOK) return;
  const float* xr = x + (size_t)wave * 768;
  float part[12];
  #pragma unroll
  for (int j = 0; j < 12; j++) part[j] = 0.f;
  for (int k = lane; k < 768; k += 64){
    float xv = xr[k];
    #pragma unroll
    for (int r = 0; r < 4; r++){
      part[r]     += xv * Aq[r*768 + k];
      part[4 + r] += xv * Ak[r*768 + k];
      part[8 + r] += xv * Av[r*768 + k];
    }
  }
  #pragma unroll
  for (int j = 0; j < 12; j++){
    float v = part[j];
    #pragma unroll
    for (int off = 32; off; off >>= 1) v += __shfl_xor(v, off);
    if (lane == 0){
      int mat = j >> 2, r = j & 3;
      t[((size_t)mat * NTOK + wave) * 4 + r] = v;
    }
  }
}

// ---------------- fused qkv GEMM (+bias +LoRA, writes q(scaled),k,vT) ----------------
// v11: 128x64 tile (grid 36x18 = 648 blocks) for better CU fill vs 324.
__global__ __launch_bounds__(256) void qkv_gemm(
    const unsigned short* __restrict__ xg,   // [2304][768] bf16
    const unsigned short* __restrict__ wg,   // [2304][768] bf16
    const float* __restrict__ bias,          // [2304]
    const float* __restrict__ t,             // [3][2304][4]
    const float* __restrict__ Bq, const float* __restrict__ Bk, const float* __restrict__ Bv, // [768][4]
    unsigned short* __restrict__ qo,         // [12][2304][64]  (pre-scaled by 0.125)
    unsigned short* __restrict__ ko,         // [12][2304][64]
    unsigned short* __restrict__ vT)         // [12][64][2304]
{
  __shared__ short As[128*64];
  __shared__ short Bs[64*64];
  const int tid = threadIdx.x;
  const int lane = tid & 63;
  const int wv = tid >> 6;
  const int r = lane & 15, g = lane >> 4;
  const int wm = (wv >> 1) * 64, wn = (wv & 1) * 32;
  const int m0 = blockIdx.y * 128, n0 = blockIdx.x * 64;

  f32x4 acc[4][2];
  #pragma unroll
  for (int i = 0; i < 4; i++)
    #pragma unroll
    for (int j = 0; j < 2; j++) acc[i][j] = (f32x4){0.f, 0.f, 0.f, 0.f};

  for (int k0 = 0; k0 < 768; k0 += 64){
    __syncthreads();
    #pragma unroll
    for (int it = 0; it < 4; it++){
      int f = it * 256 + tid;
      int row = f >> 3, u = f & 7;
      int us = ((u ^ (row & 7)) << 3);
      gload_lds16(xg + (size_t)(m0 + row) * 768 + k0 + us, &As[f * 8]);
    }
    #pragma unroll
    for (int it = 0; it < 2; it++){
      int f = it * 256 + tid;
      int row = f >> 3, u = f & 7;
      int us = ((u ^ (row & 7)) << 3);
      gload_lds16(wg + (size_t)(n0 + row) * 768 + k0 + us, &Bs[f * 8]);
    }
    __syncthreads();
    #pragma unroll
    for (int ks = 0; ks < 2; ks++){
      bf16x8 af[4], bfr[2];
      #pragma unroll
      for (int mt = 0; mt < 4; mt++){
        int row = wm + mt * 16 + r;
        af[mt] = *(const bf16x8*)&As[row * 64 + ((((ks << 2) | g) ^ (r & 7)) << 3)];
      }
      #pragma unroll
      for (int nt = 0; nt < 2; nt++){
        int row = wn + nt * 16 + r;
        bfr[nt] = *(const bf16x8*)&Bs[row * 64 + ((((ks << 2) | g) ^ (r & 7)) << 3)];
      }
      #pragma unroll
      for (int mt = 0; mt < 4; mt++)
        #pragma unroll
        for (int nt = 0; nt < 2; nt++)
          acc[mt][nt] = __builtin_amdgcn_mfma_f32_16x16x32_bf16(af[mt], bfr[nt], acc[mt][nt], 0, 0, 0);
    }
  }

  const int part = n0 / 768;   // 64 | 768 -> block never straddles parts
  const float* Bl = (part == 0) ? Bq : ((part == 1) ? Bk : Bv);
  const float* tp = t + (size_t)part * NTOK * 4;
  #pragma unroll
  for (int mt = 0; mt < 4; mt++){
    #pragma unroll
    for (int reg = 0; reg < 4; reg++){
      int row_m = m0 + wm + mt * 16 + g * 4 + reg;
      float4 tv = *(const float4*)&tp[row_m * 4];
      #pragma unroll
      for (int nt = 0; nt < 2; nt++){
        int col = n0 + wn + nt * 16 + r;
        int cc = col - part * 768;
        float4 bw = *(const float4*)&Bl[cc * 4];
        float val = acc[mt][nt][reg] + bias[col]
                  + 0.25f * (tv.x * bw.x + tv.y * bw.y + tv.z * bw.z + tv.w * bw.w);
        int head = cc >> 6, d = cc & 63;
        if (part == 0)      qo[((size_t)head * NTOK + row_m) * 64 + d] = f2bf(val * 0.125f);
        else if (part == 1) ko[((size_t)head * NTOK + row_m) * 64 + d] = f2bf(val);
        else                vT[((size_t)head * 64 + d) * NTOK + row_m] = f2bf(val);
      }
    }
  }
}

// ---------------- rel_h / rel_w via MFMA (rel_pos converted in-kernel) ----------------
__global__ __launch_bounds__(256, 2) void rel_gemm(
    const unsigned short* __restrict__ qg,    // [12][2304][64] bf16 (scaled by 0.125)
    const float* __restrict__ rph,            // [95][64] f32
    const float* __restrict__ rpw,            // [95][64] f32
    float* __restrict__ rel_h,                // [12][2304][48]
    float* __restrict__ rel_w)                // [12][2304][48]
{
  __shared__ float G[48 * 196];
  const int ih = blockIdx.x, head = blockIdx.y;
  const int tid = threadIdx.x, lane = tid & 63, wv = tid >> 6;
  const int r = lane & 15, g = lane >> 4;
  const int q0 = ih * 48;

  bf16x8 af[3][2];
  #pragma unroll
  for (int mt = 0; mt < 3; mt++)
    #pragma unroll
    for (int ks = 0; ks < 2; ks++)
      af[mt][ks] = *(const bf16x8*)&qg[((size_t)head * NTOK + q0 + mt * 16 + r) * 64 + ks * 32 + g * 8];

  bf16x8 bfv[3][2];
  #pragma unroll
  for (int nt = 0; nt < 3; nt++){
    int col = wv * 48 + nt * 16 + r;
    const float* src = (col < 95) ? &rph[(size_t)col * 64]
                     : (col < 190) ? &rpw[(size_t)(col - 95) * 64]
                     : &rpw[0];
    #pragma unroll
    for (int ks = 0; ks < 2; ks++){
      float4 lo = *(const float4*)&src[ks * 32 + g * 8];
      float4 hi = *(const float4*)&src[ks * 32 + g * 8 + 4];
      union { unsigned short u[8]; bf16x8 v; } t;
      t.u[0] = f2bf(lo.x); t.u[1] = f2bf(lo.y); t.u[2] = f2bf(lo.z); t.u[3] = f2bf(lo.w);
      t.u[4] = f2bf(hi.x); t.u[5] = f2bf(hi.y); t.u[6] = f2bf(hi.z); t.u[7] = f2bf(hi.w);
      bfv[nt][ks] = t.v;
    }
  }

  f32x4 acc[3][3];
  #pragma unroll
  for (int mt = 0; mt < 3; mt++)
    #pragma unroll
    for (int nt = 0; nt < 3; nt++) acc[mt][nt] = (f32x4){0.f, 0.f, 0.f, 0.f};
  #pragma unroll
  for (int ks = 0; ks < 2; ks++)
    #pragma unroll
    for (int mt = 0; mt < 3; mt++)
      #pragma unroll
      for (int nt = 0; nt < 3; nt++)
        acc[mt][nt] = __builtin_amdgcn_mfma_f32_16x16x32_bf16(af[mt][ks], bfv[nt][ks], acc[mt][nt], 0, 0, 0);

  #pragma unroll
  for (int mt = 0; mt < 3; mt++)
    #pragma unroll
    for (int reg = 0; reg < 4; reg++){
      int row = mt * 16 + g * 4 + reg;
      #pragma unroll
      for (int nt = 0; nt < 3; nt++)
        G[row * 196 + wv * 48 + nt * 16 + r] = acc[mt][nt][reg];
    }
  __syncthreads();

  for (int idx = tid; idx < 48 * 96; idx += 256){
    int i = idx / 96, c = idx % 96;
    size_t gi = (size_t)head * NTOK + q0 + i;
    if (c < 48) rel_h[gi * 48 + c]        = G[i * 196 + (ih + 47 - c)] * 8.f;
    else        rel_w[gi * 48 + (c - 48)] = G[i * 196 + 95 + (i + 47 - (c - 48))] * 8.f;
  }
}

// ---------------- flash attention v9 (R10-exact, passing) ----------------
__global__ __launch_bounds__(256, 3) void attn_kernel(
    const unsigned short* __restrict__ qg,   // [12][2304][64] scaled
    const unsigned short* __restrict__ kg,   // [12][2304][64]
    const unsigned short* __restrict__ vT,   // [12][64][2304]
    const float* __restrict__ rel_h,         // [12][2304][48]
    const float* __restrict__ rel_w,         // [12][2304][48]
    unsigned short* __restrict__ ao)         // [2304][768]
{
  // Ks[2][64][64]us @0 | Vs[2][64][64]us @16384 | relH[64][52]f32 @32768 | lsh @46080
  __shared__ __align__(16) char smem[46336];
  unsigned short* Ks = (unsigned short*)smem;
  unsigned short* Vs = (unsigned short*)(smem + 16384);
  float* relH = (float*)(smem + 32768);
  float* lsh = (float*)(smem + 46080);

  const int head = blockIdx.y;
  const int q0 = blockIdx.x * 64;
  const int tid = threadIdx.x, lane = tid & 63, wv = tid >> 6;
  const int r = lane & 15, g = lane >> 4;

  const unsigned short* kbase = kg + (size_t)head * NTOK * 64;
  const unsigned short* vbase = vT + (size_t)head * 64 * NTOK;

  // rel_h stage (f32, stride 52 -> 16B-aligned rows, float4)
  for (int idx = tid; idx < 64 * 12; idx += 256){
    int i = idx / 12, c4 = idx % 12;
    *(float4*)&relH[i * 52 + c4 * 4] =
        *(const float4*)&rel_h[((size_t)head * NTOK + q0 + i) * 48 + c4 * 4];
  }

  // rel_w: 3 static float4s per lane (row = wv*16+r, cols 16j+4g..+3), full f32
  float4 wreg[3];
  #pragma unroll
  for (int j = 0; j < 3; j++)
    wreg[j] = *(const float4*)&rel_w[((size_t)head * NTOK + q0 + wv * 16 + r) * 48 + j * 16 + g * 4];

  bf16x8 qf[2];
  #pragma unroll
  for (int ks = 0; ks < 2; ks++)
    qf[ks] = *(const bf16x8*)&qg[((size_t)head * NTOK + q0 + wv * 16 + r) * 64 + ks * 32 + g * 8];

  const int rowIn = lane >> 3, uu = lane & 7;

  // prologue: stage tile 0 into buf 0
  #pragma unroll
  for (int s2 = 0; s2 < 2; s2++){
    int seg = wv * 2 + s2;
    int row = seg * 8 + rowIn;
    gload_lds16(kbase + (size_t)row * 64 + ((uu ^ (row & 7)) << 3), &Ks[seg * 512 + lane * 8]);
    gload_lds16(vbase + (size_t)row * NTOK + ((uu ^ (row & 7)) << 3), &Vs[seg * 512 + lane * 8]);
  }
  __syncthreads();

  f32x4 Oa[4];
  float lrun = 0.f;
  #pragma unroll
  for (int dt = 0; dt < 4; dt++) Oa[dt] = (f32x4){0.f, 0.f, 0.f, 0.f};

  const float* rsh = &relH[(wv * 16 + r) * 52];

  // e = 4t+ntl, t = 3a+tb -> kh = 4a + KH[tb][ntl], j = J[tb][ntl]
  const int KH_T[3][4] = {{0,0,0,1},{1,1,2,2},{2,3,3,3}};
  const int J_T[3][4]  = {{0,1,2,0},{1,2,0,1},{2,0,1,2}};

  const int srcA = r + ((g & 1) << 5);   // lane (r, 2*(g&1))
  const int srcB = srcA + 16;            // lane (r, 2*(g&1)+1)
  const int hi = (g >> 1);

  int buf = 0;
  for (int a = 0; a < 12; a++){
    #pragma unroll
    for (int tb = 0; tb < 3; tb++){
      const int t = a * 3 + tb;
      unsigned short* KsB = &Ks[buf * 4096];
      unsigned short* VsB = &Vs[buf * 4096];

      if (t < 35){
        const int key0n = (t + 1) * 64;
        unsigned short* KsN = &Ks[(buf ^ 1) * 4096];
        unsigned short* VsN = &Vs[(buf ^ 1) * 4096];
        #pragma unroll
        for (int s2 = 0; s2 < 2; s2++){
          int seg = wv * 2 + s2;
          int row = seg * 8 + rowIn;
          gload_lds16(kbase + (size_t)(key0n + row) * 64 + ((uu ^ (row & 7)) << 3),
                      &KsN[seg * 512 + lane * 8]);
          gload_lds16(vbase + (size_t)row * NTOK + key0n + ((uu ^ (row & 7)) << 3),
                      &VsN[seg * 512 + lane * 8]);
        }
      }

      // ---- QK^T (swapped): s[ntl] = S[key=16ntl+4g+reg][q=r] ----
      f32x4 s[4];
      __builtin_amdgcn_s_setprio(1);
      #pragma unroll
      for (int ntl = 0; ntl < 4; ntl++){
        bf16x8 kc0 = *(const bf16x8*)&KsB[(ntl * 16 + r) * 64 + ((g ^ (r & 7)) << 3)];
        bf16x8 kc1 = *(const bf16x8*)&KsB[(ntl * 16 + r) * 64 + (((4 + g) ^ (r & 7)) << 3)];
        s[ntl] = (f32x4){0.f, 0.f, 0.f, 0.f};
        s[ntl] = __builtin_amdgcn_mfma_f32_16x16x32_bf16(kc0, qf[0], s[ntl], 0, 0, 0);
        s[ntl] = __builtin_amdgcn_mfma_f32_16x16x32_bf16(kc1, qf[1], s[ntl], 0, 0, 0);
      }
      __builtin_amdgcn_s_setprio(0);

      // ---- bias + exp + pack (W0/W1 per ntl) ----
      unsigned W0[4], W1[4];
      #pragma unroll
      for (int ntl = 0; ntl < 4; ntl++){
        float bh = rsh[4 * a + KH_T[tb][ntl]];
        float4 w = wreg[J_T[tb][ntl]];
        float p0 = __expf(s[ntl][0] + bh + w.x);
        float p1 = __expf(s[ntl][1] + bh + w.y);
        float p2 = __expf(s[ntl][2] + bh + w.z);
        float p3 = __expf(s[ntl][3] + bh + w.w);
        lrun += (p0 + p1) + (p2 + p3);
        asm("v_cvt_pk_bf16_f32 %0, %1, %2" : "=v"(W0[ntl]) : "v"(p0), "v"(p1));
        asm("v_cvt_pk_bf16_f32 %0, %1, %2" : "=v"(W1[ntl]) : "v"(p2), "v"(p3));
      }

      // ---- in-register P redistribution: pf[ks] elem j = key 32ks+8g+j ----
      bf16x8 pf[2];
      #pragma unroll
      for (int ks = 0; ks < 2; ks++){
        unsigned a0 = (unsigned)__shfl((int)W0[2*ks],   srcA);
        unsigned a1 = (unsigned)__shfl((int)W0[2*ks+1], srcA);
        unsigned b0 = (unsigned)__shfl((int)W1[2*ks],   srcA);
        unsigned b1 = (unsigned)__shfl((int)W1[2*ks+1], srcA);
        unsigned c0 = (unsigned)__shfl((int)W0[2*ks],   srcB);
        unsigned c1 = (unsigned)__shfl((int)W0[2*ks+1], srcB);
        unsigned d0 = (unsigned)__shfl((int)W1[2*ks],   srcB);
        unsigned d1 = (unsigned)__shfl((int)W1[2*ks+1], srcB);
        union { unsigned w[4]; bf16x8 v; } u;
        u.w[0] = hi ? a1 : a0;
        u.w[1] = hi ? b1 : b0;
        u.w[2] = hi ? c1 : c0;
        u.w[3] = hi ? d1 : d0;
        pf[ks] = u.v;
      }

      // ---- PV ----
      __builtin_amdgcn_s_setprio(1);
      #pragma unroll
      for (int dt = 0; dt < 4; dt++){
        #pragma unroll
        for (int ks = 0; ks < 2; ks++){
          bf16x8 vf = *(const bf16x8*)&VsB[(dt * 16 + r) * 64 + (((ks * 4 + g) ^ (r & 7)) << 3)];
          Oa[dt] = __builtin_amdgcn_mfma_f32_16x16x32_bf16(pf[ks], vf, Oa[dt], 0, 0, 0);
        }
      }
      __builtin_amdgcn_s_setprio(0);

      __syncthreads();   // drains stage loads + protects buf swap
      buf ^= 1;
    }
  }

  // ---- epilogue ----
  {
    float l = lrun;
    l += __shfl_xor(l, 16);
    l += __shfl_xor(l, 32);
    if (lane < 16) lsh[wv * 16 + lane] = l;
  }
  __syncthreads();
  float invL[4];
  #pragma unroll
  for (int reg = 0; reg < 4; reg++) invL[reg] = 1.f / lsh[wv * 16 + g * 4 + reg];
  #pragma unroll
  for (int dt = 0; dt < 4; dt++)
    #pragma unroll
    for (int reg = 0; reg < 4; reg++){
      int token = q0 + wv * 16 + g * 4 + reg;
      ao[(size_t)token * 768 + head * 64 + dt * 16 + r] = f2bf(Oa[dt][reg] * invL[reg]);
    }
}

// ---------------- proj GEMM ----------------
// v11: 64x64 tile (grid 12x36 = 432 blocks) for better CU fill vs 108.
__global__ __launch_bounds__(256) void proj_gemm(
    const unsigned short* __restrict__ ag,   // [2304][768] bf16
    const unsigned short* __restrict__ wg,   // [768][768] bf16
    const float* __restrict__ bias,
    float* __restrict__ out)
{
  __shared__ short As[64*64];
  __shared__ short Bs[64*64];
  const int tid = threadIdx.x;
  const int lane = tid & 63;
  const int wv = tid >> 6;
  const int r = lane & 15, g = lane >> 4;
  const int wm = (wv >> 1) * 32, wn = (wv & 1) * 32;
  const int m0 = blockIdx.y * 64, n0 = blockIdx.x * 64;

  f32x4 acc[2][2];
  #pragma unroll
  for (int i = 0; i < 2; i++)
    #pragma unroll
    for (int j = 0; j < 2; j++) acc[i][j] = (f32x4){0.f, 0.f, 0.f, 0.f};

  for (int k0 = 0; k0 < 768; k0 += 64){
    __syncthreads();
    #pragma unroll
    for (int it = 0; it < 2; it++){
      int f = it * 256 + tid;
      int row = f >> 3, u = f & 7;
      int us = ((u ^ (row & 7)) << 3);
      gload_lds16(ag + (size_t)(m0 + row) * 768 + k0 + us, &As[f * 8]);
      gload_lds16(wg + (size_t)(n0 + row) * 768 + k0 + us, &Bs[f * 8]);
    }
    __syncthreads();
    #pragma unroll
    for (int ks = 0; ks < 2; ks++){
      bf16x8 af[2], bfr[2];
      #pragma unroll
      for (int mt = 0; mt < 2; mt++){
        int row = wm + mt * 16 + r;
        af[mt] = *(const bf16x8*)&As[row * 64 + ((((ks << 2) | g) ^ (r & 7)) << 3)];
      }
      #pragma unroll
      for (int nt = 0; nt < 2; nt++){
        int row = wn + nt * 16 + r;
        bfr[nt] = *(const bf16x8*)&Bs[row * 64 + ((((ks << 2) | g) ^ (r & 7)) << 3)];
      }
      #pragma unroll
      for (int mt = 0; mt < 2; mt++)
        #pragma unroll
        for (int nt = 0; nt < 2; nt++)
          acc[mt][nt] = __builtin_amdgcn_mfma_f32_16x16x32_bf16(af[mt], bfr[nt], acc[mt][nt], 0, 0, 0);
    }
  }

  #pragma unroll
  for (int mt = 0; mt < 2; mt++)
    #pragma unroll
    for (int reg = 0; reg < 4; reg++){
      int row_m = m0 + wm + mt * 16 + g * 4 + reg;
      #pragma unroll
      for (int nt = 0; nt < 2; nt++){
        int col = n0 + wn + nt * 16 + r;
        out[(size_t)row_m * 768 + col] = acc[mt][nt][reg] + bias[col];
      }
    }
}

extern "C" void kernel_launch(void* const* d_in, const int* in_sizes, int n_in,
                              void* d_out, int out_size, void* d_ws, size_t ws_size,
                              hipStream_t stream){
  (void)in_sizes; (void)n_in; (void)out_size; (void)ws_size;
  const float* x      = (const float*)d_in[0];
  const float* qkv_w  = (const float*)d_in[1];
  const float* qkv_b  = (const float*)d_in[2];
  const float* proj_w = (const float*)d_in[3];
  const float* proj_b = (const float*)d_in[4];
  const float* rph    = (const float*)d_in[5];
  const float* rpw    = (const float*)d_in[6];
  const float* Aq     = (const float*)d_in[7];
  const float* Bq     = (const float*)d_in[8];
  const float* Ak     = (const float*)d_in[9];
  const float* Bk     = (const float*)d_in[10];
  const float* Av     = (const float*)d_in[11];
  const float* Bv     = (const float*)d_in[12];

  char* w = (char*)d_ws;
  unsigned short* xb  = (unsigned short*)(w + 0);         // 2304*768 bf16
  unsigned short* wqb = (unsigned short*)(w + 3538944);   // 2304*768 bf16
  unsigned short* wpb = (unsigned short*)(w + 7077888);   //  768*768 bf16
  unsigned short* qb  = (unsigned short*)(w + 8257536);   // 12*2304*64 bf16 (scaled)
  unsigned short* kb  = (unsigned short*)(w + 11796480);  // 12*2304*64 bf16
  unsigned short* vtb = (unsigned short*)(w + 15335424);  // 12*64*2304 bf16
  float* tb           = (float*)(w + 18874368);           // 3*2304*4 f32
  float* rhb          = (float*)(w + 18984960);           // 12*2304*48 f32
  float* rwb          = (float*)(w + 24293376);           // 12*2304*48 f32
  unsigned short* aob = (unsigned short*)(w + 29601792);  // 2304*768 bf16

  cvt_all<<<4032, 256, 0, stream>>>(x, qkv_w, proj_w, xb, wqb, wpb);
  lora_t_kernel<<<576, 256, 0, stream>>>(x, Aq, Ak, Av, tb);
  qkv_gemm<<<dim3(36, 18), 256, 0, stream>>>(xb, wqb, qkv_b, tb, Bq, Bk, Bv, qb, kb, vtb);
  rel_gemm<<<dim3(48, 12), 256, 0, stream>>>(qb, rph, rpw, rhb, rwb);
  attn_kernel<<<dim3(36, 12), 256, 0, stream>>>(qb, kb, vtb, rhb, rwb, aob);
  proj_gemm<<<dim3(12, 36), 256, 0, stream>>>(aob, wpb, proj_b, (float*)d_out);
}